// Round 2
// baseline (11783.075 us; speedup 1.0000x reference)
//
#include <hip/hip_runtime.h>
#include <hip/hip_bf16.h>
#include <cstdint>
#include <cstddef>

// LearnableCA fire-spread. fp32 compute, bf16 activation storage, batch-chunked
// to adapt to ws_size (prev round likely overran d_ws with a 672 MB layout).
// Pipeline: setup -> [per batch-chunk] conv1(22->64) -> conv2(64->64) ->
// 5x [per chunk: cw1(68->64, one-hot fused) -> cw2(64->32) -> 1x1+softmax+wind+update]

#define HPIX 256
#define WPIX 256
#define HWSZ 65536

typedef __hip_bfloat16 bf16;
struct bpack4 { bf16 h[4]; };  // 8-byte bf16x4 store

// ---- transpose conv weights [COUT][CINF][3][3] -> [CINF][9][COUT] ----
__global__ void k_wtrans(const float* __restrict__ src, float* __restrict__ dst,
                         int COUT, int CINF) {
  int i = blockIdx.x * 256 + threadIdx.x;
  int total = COUT * CINF * 9;
  if (i >= total) return;
  int co = i / (CINF * 9);
  int rem = i - co * (CINF * 9);
  int ci = rem / 9;
  int tap = rem - ci * 9;
  dst[(ci * 9 + tap) * COUT + co] = src[i];
}

// ---- fold BN + conv bias into per-channel scale/shift ----
__global__ void k_bnfuse(const float* __restrict__ g, const float* __restrict__ be,
                         const float* __restrict__ m, const float* __restrict__ v,
                         const float* __restrict__ bc, float* __restrict__ s,
                         float* __restrict__ t, int C) {
  int c = threadIdx.x;
  if (c < C) {
    float sc = g[c] * rsqrtf(v[c] + 1e-5f);
    s[c] = sc;
    t[c] = (bc[c] - m[c]) * sc + be[c];
  }
}

// ---- per-batch wind gate: mean(ch7), mean(ch8) -> effective 3x3 kernel ----
__global__ void k_windgate(const float* __restrict__ env, const float* __restrict__ wind_k,
                           float* __restrict__ wke) {
  int b = blockIdx.x;
  const float* a7 = env + (((size_t)(b * 22 + 7)) << 16);
  const float* a8 = env + (((size_t)(b * 22 + 8)) << 16);
  double s7 = 0.0, s8 = 0.0;
  for (int i = threadIdx.x; i < HWSZ; i += 256) { s7 += a7[i]; s8 += a8[i]; }
  __shared__ double r7[256], r8[256];
  r7[threadIdx.x] = s7; r8[threadIdx.x] = s8;
  __syncthreads();
  for (int off = 128; off > 0; off >>= 1) {
    if (threadIdx.x < off) {
      r7[threadIdx.x] += r7[threadIdx.x + off];
      r8[threadIdx.x] += r8[threadIdx.x + off];
    }
    __syncthreads();
  }
  if (threadIdx.x == 0) {
    float wa = (float)(r7[0] * (1.0 / 65536.0));
    float wsp = (float)(r8[0] * (1.0 / 65536.0));
    float wsc = fminf(fmaxf(wsp * (1.f / 20.f), 0.f), 1.f);
    float wk[9];
#pragma unroll
    for (int tp = 0; tp < 9; ++tp) wk[tp] = 0.f;
    for (int d = 0; d < 8; ++d) {
      float diff = fabsf(wa - 45.f * (float)d);
      diff = fminf(diff, 360.f - diff);
      float dw = fmaxf(0.f, 1.f - diff * (1.f / 90.f));
      float eff = (dw > 0.1f && wsc > 0.1f) ? dw * wsc : 0.f;
      for (int tp = 0; tp < 9; ++tp) wk[tp] += eff * wind_k[d * 9 + tp];
    }
    for (int tp = 0; tp < 9; ++tp) wke[b * 9 + tp] = wk[tp];
  }
}

__global__ void k_copy(const float* __restrict__ src, float* __restrict__ dst) {
  int i = blockIdx.x * 256 + threadIdx.x;
  ((float4*)dst)[i] = ((const float4*)src)[i];
}

// ---- generic 3x3 conv + scale/shift + relu; optional fused one-hot channels ----
// x: [NB, CIN, 256,256] (TX = float or bf16); wT: [CIN(+4)][9][COUT]; y: bf16.
// Tile: 32 cout x (4h x 32w). 256 threads: tid = (hl<<6)|(wq<<3)|co4g.
template <int CIN, int COUT, bool ONEHOT, typename TX>
__global__ __launch_bounds__(256) void k_conv3x3(
    const TX* __restrict__ x, const float* __restrict__ wT,
    const float* __restrict__ scale, const float* __restrict__ shift,
    const float* __restrict__ fire, bf16* __restrict__ y) {
  constexpr int WT = 32, HT = 4, COT = 32, CK = 8;
  __shared__ float xs[CK][HT + 2][WT + 3];
  __shared__ float wl[CK][9][COT];
  __shared__ float ohw[ONEHOT ? 4 : 1][ONEHOT ? 9 : 1][ONEHOT ? COT : 1];
  __shared__ int idxs[ONEHOT ? (HT + 2) : 1][ONEHOT ? (WT + 2) : 1];

  int bx = blockIdx.x;
  int tw = bx & 7;
  int th = (bx >> 3) & 63;
  int b = bx >> 9;  // chunk-local batch
  int coB = blockIdx.y * COT;
  int tid = threadIdx.x;
  int co4 = (tid & 7) * 4;
  int wq = ((tid >> 3) & 7) * 4;
  int hl = tid >> 6;
  int h0 = th * HT, w0 = tw * WT;

  float acc[4][4];
#pragma unroll
  for (int i = 0; i < 4; ++i)
#pragma unroll
    for (int j = 0; j < 4; ++j) acc[i][j] = 0.f;

  if (ONEHOT) {
    for (int i = tid; i < (HT + 2) * (WT + 2); i += 256) {
      int r = i / (WT + 2), cc = i - r * (WT + 2);
      int hh = h0 + r - 1, ww = w0 + cc - 1;
      int id = 3;  // border -> zero contribution (SAME zero padding)
      if ((unsigned)hh < HPIX && (unsigned)ww < WPIX) {
        float f = fire[((size_t)b << 16) + (hh << 8) + ww];
        id = f < 0.25f ? 0 : (f < 0.75f ? 1 : 2);
      }
      idxs[r][cc] = id;
    }
    for (int i = tid; i < 4 * 9 * COT; i += 256) {
      int c = i / (9 * COT);
      int rem = i - c * (9 * COT);
      int tap = rem / COT, co = rem - tap * COT;
      float v = 0.f;
      if (c < 3) v = wT[((size_t)(CIN + c) * 9 + tap) * COUT + coB + co];
      (&ohw[0][0][0])[i] = v;
    }
  }

  int nck = (CIN + CK - 1) / CK;
  for (int chb = 0; chb < nck; ++chb) {
    int cbase = chb * CK;
    int ck = CIN - cbase;
    if (ck > CK) ck = CK;
    __syncthreads();
    for (int i = tid; i < ck * (HT + 2) * (WT + 2); i += 256) {
      int c = i / ((HT + 2) * (WT + 2));
      int rem = i - c * ((HT + 2) * (WT + 2));
      int r = rem / (WT + 2), cc = rem - r * (WT + 2);
      int hh = h0 + r - 1, ww = w0 + cc - 1;
      float v = 0.f;
      if ((unsigned)hh < HPIX && (unsigned)ww < WPIX)
        v = (float)x[((size_t)(b * CIN + cbase + c) << 16) + (hh << 8) + ww];
      xs[c][r][cc] = v;
    }
    for (int i = tid; i < ck * 9 * COT; i += 256) {
      int c = i / (9 * COT);
      int rem = i - c * (9 * COT);
      int tap = rem / COT, co = rem - tap * COT;
      wl[c][tap][co] = wT[((size_t)(cbase + c) * 9 + tap) * COUT + coB + co];
    }
    __syncthreads();
    for (int c = 0; c < ck; ++c) {
      float r0[6], r1[6], r2[6];
#pragma unroll
      for (int j = 0; j < 6; ++j) {
        r0[j] = xs[c][hl + 0][wq + j];
        r1[j] = xs[c][hl + 1][wq + j];
        r2[j] = xs[c][hl + 2][wq + j];
      }
#pragma unroll
      for (int tap = 0; tap < 9; ++tap) {
        int dy = tap / 3, dx = tap - dy * 3;
        float4 wv = *(const float4*)&wl[c][tap][co4];
#pragma unroll
        for (int wi = 0; wi < 4; ++wi) {
          float xv = (dy == 0 ? r0 : (dy == 1 ? r1 : r2))[dx + wi];
          acc[0][wi] += wv.x * xv;
          acc[1][wi] += wv.y * xv;
          acc[2][wi] += wv.z * xv;
          acc[3][wi] += wv.w * xv;
        }
      }
    }
  }

  if (ONEHOT) {
#pragma unroll
    for (int tap = 0; tap < 9; ++tap) {
      int dy = tap / 3, dx = tap - dy * 3;
#pragma unroll
      for (int wi = 0; wi < 4; ++wi) {
        int id = idxs[hl + dy][wq + dx + wi];
        acc[0][wi] += ohw[id][tap][co4 + 0];
        acc[1][wi] += ohw[id][tap][co4 + 1];
        acc[2][wi] += ohw[id][tap][co4 + 2];
        acc[3][wi] += ohw[id][tap][co4 + 3];
      }
    }
  }

#pragma unroll
  for (int ci = 0; ci < 4; ++ci) {
    int co = coB + co4 + ci;
    float s = scale[co], t = shift[co];
    bpack4 o;
#pragma unroll
    for (int wi = 0; wi < 4; ++wi)
      o.h[wi] = __float2bfloat16(fmaxf(acc[ci][wi] * s + t, 0.f));
    *(bpack4*)&y[((size_t)(b * COUT + co) << 16) + ((h0 + hl) << 8) + w0 + wq] = o;
  }
}

// ---- fused 1x1 conv (32->4) + softmax + wind conv + fire update ----
__global__ __launch_bounds__(256) void k_step(
    const bf16* __restrict__ h2, const float* __restrict__ cw3,
    const float* __restrict__ cb3, const float* __restrict__ wke,
    const float* __restrict__ fin, float* __restrict__ fout,
    float* __restrict__ fout2) {
  __shared__ float wl[4][32];
  __shared__ float bl[4];
  __shared__ float wk[9];
  int tid = threadIdx.x;
  if (tid < 128) wl[tid >> 5][tid & 31] = cw3[tid];
  if (tid < 4) bl[tid] = cb3[tid];
  int bx = blockIdx.x;
  int b = bx >> 8, h = bx & 255;  // chunk-local b
  if (tid < 9) wk[tid] = wke[b * 9 + tid];
  __syncthreads();
  int w = tid;
  const bf16* hp = h2 + (((size_t)b * 32) << 16) + (h << 8) + w;
  float l0 = bl[0], l1 = bl[1], l2 = bl[2], l3 = bl[3];
#pragma unroll
  for (int c = 0; c < 32; ++c) {
    float v = __bfloat162float(hp[(size_t)c << 16]);
    l0 += v * wl[0][c];
    l1 += v * wl[1][c];
    l2 += v * wl[2][c];
    l3 += v * wl[3][c];
  }
  float mx = fmaxf(fmaxf(l0, l1), fmaxf(l2, l3));
  float e0 = expf(l0 - mx), e1 = expf(l1 - mx), e2 = expf(l2 - mx), e3 = expf(l3 - mx);
  float inv = 1.f / (e0 + e1 + e2 + e3);
  float p1 = e1 * inv, p2 = e2 * inv;
  const float* fp = fin + ((size_t)b << 16);
  float wacc = 0.f;
#pragma unroll
  for (int tap = 0; tap < 9; ++tap) {
    int dy = tap / 3 - 1, dx = tap % 3 - 1;
    int hh = h + dy, ww2 = w + dx;
    float f = ((unsigned)hh < 256u && (unsigned)ww2 < 256u) ? fp[(hh << 8) + ww2] : 0.f;
    wacc += wk[tap] * f;
  }
  float boost = 0.3f / (1.f + expf(-wacc));
  float fcur = fp[(h << 8) + w];
  float target = 0.5f * p1 + 0.5f * boost + p2;
  float fn = 0.7f * fcur + 0.3f * target;
  fn = fminf(fmaxf(fn, 0.f), 1.f);
  size_t o = ((size_t)b << 16) + (h << 8) + w;
  fout[o] = fn;
  if (fout2) fout2[o] = fn;
}

extern "C" void kernel_launch(void* const* d_in, const int* in_sizes, int n_in,
                              void* d_out, int out_size, void* d_ws, size_t ws_size,
                              hipStream_t stream) {
  const float* env = (const float*)d_in[0];
  const float* fire0 = (const float*)d_in[1];
  const float* w1 = (const float*)d_in[2];
  const float* b1 = (const float*)d_in[3];
  const float* g1 = (const float*)d_in[4];
  const float* be1 = (const float*)d_in[5];
  const float* m1 = (const float*)d_in[6];
  const float* v1 = (const float*)d_in[7];
  const float* w2 = (const float*)d_in[8];
  const float* b2 = (const float*)d_in[9];
  const float* g2 = (const float*)d_in[10];
  const float* be2 = (const float*)d_in[11];
  const float* m2 = (const float*)d_in[12];
  const float* v2 = (const float*)d_in[13];
  const float* cw1 = (const float*)d_in[14];
  const float* cb1 = (const float*)d_in[15];
  const float* cg1 = (const float*)d_in[16];
  const float* cbe1 = (const float*)d_in[17];
  const float* cm1 = (const float*)d_in[18];
  const float* cv1 = (const float*)d_in[19];
  const float* cw2 = (const float*)d_in[20];
  const float* cb2 = (const float*)d_in[21];
  const float* cg2 = (const float*)d_in[22];
  const float* cbe2 = (const float*)d_in[23];
  const float* cm2 = (const float*)d_in[24];
  const float* cv2 = (const float*)d_in[25];
  const float* cw3 = (const float*)d_in[26];
  const float* cb3 = (const float*)d_in[27];
  const float* windk = (const float*)d_in[28];
  // d_in[29] = num_steps (fixed at 5 for this problem).

  float* out = (float*)d_out;
  float* evo = out + 1048576;  // [6][16][1][256][256] fp32

  // ---- workspace layout (adaptive batch chunk NB) ----
  float* ws = (float*)d_ws;
  float* wT1 = ws;                       // 22*9*64   = 12672
  float* wT2 = wT1 + 22 * 9 * 64;        // 64*9*64   = 36864
  float* wTc1 = wT2 + 64 * 9 * 64;       // 68*9*64   = 39168
  float* wTc2 = wTc1 + 68 * 9 * 64;      // 64*9*32   = 18432
  float* s1 = wTc2 + 64 * 9 * 32;
  float* t1 = s1 + 64;
  float* s2 = t1 + 64;
  float* t2 = s2 + 64;
  float* sc1 = t2 + 64;
  float* tc1 = sc1 + 64;
  float* sc2 = tc1 + 64;
  float* tc2 = sc2 + 32;
  float* wke = tc2 + 32;                 // 16*9 = 144
  size_t fp32_floats = (size_t)(wke - ws) + 160;  // pad to 16B multiple region
  fp32_floats = (fp32_floats + 7) & ~(size_t)7;

  const size_t ENV_E = (size_t)16 * 64 * HWSZ;       // bf16 elems
  bf16* envf = (bf16*)(ws + fp32_floats);
  size_t base_bytes = fp32_floats * 4 + ENV_E * 2;
  int NB = 1;
  for (int nb = 16; nb >= 1; nb >>= 1) {
    size_t need = base_bytes + (size_t)nb * (64 + 32) * HWSZ * 2;
    if (need <= ws_size) { NB = nb; break; }
  }
  bf16* h1 = envf + ENV_E;                            // NB*64*HWSZ
  bf16* h2 = h1 + (size_t)NB * 64 * HWSZ;             // NB*32*HWSZ

  k_wtrans<<<(64 * 22 * 9 + 255) / 256, 256, 0, stream>>>(w1, wT1, 64, 22);
  k_wtrans<<<(64 * 64 * 9 + 255) / 256, 256, 0, stream>>>(w2, wT2, 64, 64);
  k_wtrans<<<(64 * 68 * 9 + 255) / 256, 256, 0, stream>>>(cw1, wTc1, 64, 68);
  k_wtrans<<<(32 * 64 * 9 + 255) / 256, 256, 0, stream>>>(cw2, wTc2, 32, 64);
  k_bnfuse<<<1, 256, 0, stream>>>(g1, be1, m1, v1, b1, s1, t1, 64);
  k_bnfuse<<<1, 256, 0, stream>>>(g2, be2, m2, v2, b2, s2, t2, 64);
  k_bnfuse<<<1, 256, 0, stream>>>(cg1, cbe1, cm1, cv1, cb1, sc1, tc1, 64);
  k_bnfuse<<<1, 256, 0, stream>>>(cg2, cbe2, cm2, cv2, cb2, sc2, tc2, 32);
  k_windgate<<<16, 256, 0, stream>>>(env, windk, wke);
  k_copy<<<1024, 256, 0, stream>>>(fire0, evo);

  dim3 blk(256);
  // encoder, chunked
  for (int b0 = 0; b0 < 16; b0 += NB) {
    dim3 gc(NB * 512, 2);
    k_conv3x3<22, 64, false, float><<<gc, blk, 0, stream>>>(
        env + (size_t)b0 * 22 * HWSZ, wT1, s1, t1, nullptr, h1);
    k_conv3x3<64, 64, false, bf16><<<gc, blk, 0, stream>>>(
        h1, wT2, s2, t2, nullptr, envf + (size_t)b0 * 64 * HWSZ);
  }
  // CA steps, chunked
  for (int t = 0; t < 5; ++t) {
    const float* fin = evo + (size_t)t * 1048576;
    float* fo = evo + (size_t)(t + 1) * 1048576;
    for (int b0 = 0; b0 < 16; b0 += NB) {
      dim3 gc64(NB * 512, 2), gc32(NB * 512, 1);
      k_conv3x3<64, 64, true, bf16><<<gc64, blk, 0, stream>>>(
          envf + (size_t)b0 * 64 * HWSZ, wTc1, sc1, tc1, fin + (size_t)b0 * HWSZ, h1);
      k_conv3x3<64, 32, false, bf16><<<gc32, blk, 0, stream>>>(
          h1, wTc2, sc2, tc2, nullptr, h2);
      k_step<<<NB * 256, 256, 0, stream>>>(
          h2, cw3, cb3, wke + (size_t)b0 * 9, fin + (size_t)b0 * HWSZ,
          fo + (size_t)b0 * HWSZ, (t == 4) ? out + (size_t)b0 * HWSZ : nullptr);
    }
  }
}

// Round 3
// 1643.051 us; speedup vs baseline: 7.1715x; 7.1715x over previous
//
#include <hip/hip_runtime.h>
#include <cstdint>
#include <cstddef>

// LearnableCA fire-spread, round 3: fp16 MFMA implicit-GEMM for the three
// 64-channel convs; conv1 stays fp32 VALU (env ch7 ~360 needs precision).
// Activations: padded NHWC fp16 [b][258][258][64] (zero borders via memset).
// K-order: k = tap*64 + ci (18 slices of 32); one-hot = 2 extra slices.

#define HWSZ 65536

typedef _Float16 f16;
typedef f16 f16x8 __attribute__((ext_vector_type(8)));
typedef f16 f16x4 __attribute__((ext_vector_type(4)));
typedef float f32x4 __attribute__((ext_vector_type(4)));

#define GLDS16(gp, lp)                                                        \
  __builtin_amdgcn_global_load_lds(                                           \
      (const __attribute__((address_space(1))) void*)(gp),                    \
      (__attribute__((address_space(3))) void*)(lp), 16, 0, 0)

// ---- weight transpose for fp32 conv1: [co][ci][3][3] -> [ci][9][co] ----
__global__ void k_wtrans(const float* __restrict__ src, float* __restrict__ dst,
                         int COUT, int CINF) {
  int i = blockIdx.x * 256 + threadIdx.x;
  int total = COUT * CINF * 9;
  if (i >= total) return;
  int co = i / (CINF * 9);
  int rem = i - co * (CINF * 9);
  int ci = rem / 9;
  int tap = rem - ci * 9;
  dst[(ci * 9 + tap) * COUT + co] = src[i];
}

// ---- fp16 weight prep: [co][ci 64][3][3] -> [co][tap*64+ci] ----
__global__ void k_wprep64(const float* __restrict__ src, f16* __restrict__ dst,
                          int COUT) {
  int i = blockIdx.x * 256 + threadIdx.x;
  if (i >= COUT * 576) return;
  int co = i / 576, k = i - co * 576;
  int tap = k >> 6, ci = k & 63;
  dst[i] = (f16)src[(co * 64 + ci) * 9 + tap];
}

// ---- cw1 prep: 64 normal ci + one-hot block (kl = tap*4+oc) -> [co][640] ----
__global__ void k_wprepC1(const float* __restrict__ src, f16* __restrict__ dst) {
  int i = blockIdx.x * 256 + threadIdx.x;
  if (i >= 64 * 640) return;
  int co = i / 640, k = i - co * 640;
  float v;
  if (k < 576) {
    int tap = k >> 6, ci = k & 63;
    v = src[(co * 68 + ci) * 9 + tap];
  } else {
    int kl = k - 576;
    int oc = kl & 3, tp = kl >> 2;
    v = (tp < 9) ? src[(co * 68 + 64 + oc) * 9 + tp] : 0.f;
  }
  dst[i] = (f16)v;
}

// ---- fold BN + conv bias into per-channel scale/shift ----
__global__ void k_bnfuse(const float* __restrict__ g, const float* __restrict__ be,
                         const float* __restrict__ m, const float* __restrict__ v,
                         const float* __restrict__ bc, float* __restrict__ s,
                         float* __restrict__ t, int C) {
  int c = threadIdx.x;
  if (c < C) {
    float sc = g[c] * rsqrtf(v[c] + 1e-5f);
    s[c] = sc;
    t[c] = (bc[c] - m[c]) * sc + be[c];
  }
}

// ---- per-batch wind gate ----
__global__ void k_windgate(const float* __restrict__ env, const float* __restrict__ wind_k,
                           float* __restrict__ wke) {
  int b = blockIdx.x;
  const float* a7 = env + (((size_t)(b * 22 + 7)) << 16);
  const float* a8 = env + (((size_t)(b * 22 + 8)) << 16);
  double s7 = 0.0, s8 = 0.0;
  for (int i = threadIdx.x; i < HWSZ; i += 256) { s7 += a7[i]; s8 += a8[i]; }
  __shared__ double r7[256], r8[256];
  r7[threadIdx.x] = s7; r8[threadIdx.x] = s8;
  __syncthreads();
  for (int off = 128; off > 0; off >>= 1) {
    if (threadIdx.x < off) {
      r7[threadIdx.x] += r7[threadIdx.x + off];
      r8[threadIdx.x] += r8[threadIdx.x + off];
    }
    __syncthreads();
  }
  if (threadIdx.x == 0) {
    float wa = (float)(r7[0] * (1.0 / 65536.0));
    float wsp = (float)(r8[0] * (1.0 / 65536.0));
    float wsc = fminf(fmaxf(wsp * (1.f / 20.f), 0.f), 1.f);
    float wk[9];
#pragma unroll
    for (int tp = 0; tp < 9; ++tp) wk[tp] = 0.f;
    for (int d = 0; d < 8; ++d) {
      float diff = fabsf(wa - 45.f * (float)d);
      diff = fminf(diff, 360.f - diff);
      float dw = fmaxf(0.f, 1.f - diff * (1.f / 90.f));
      float eff = (dw > 0.1f && wsc > 0.1f) ? dw * wsc : 0.f;
      for (int tp = 0; tp < 9; ++tp) wk[tp] += eff * wind_k[d * 9 + tp];
    }
    for (int tp = 0; tp < 9; ++tp) wke[b * 9 + tp] = wk[tp];
  }
}

__global__ void k_copy(const float* __restrict__ src, float* __restrict__ dst) {
  int i = blockIdx.x * 256 + threadIdx.x;
  ((float4*)dst)[i] = ((const float4*)src)[i];
}

// ---- conv1: 22->64 fp32 VALU, output padded fp16 NHWC ----
__global__ __launch_bounds__(256) void k_conv1(
    const float* __restrict__ x, const float* __restrict__ wT,
    const float* __restrict__ scale, const float* __restrict__ shift,
    f16* __restrict__ y) {
  constexpr int CIN = 22, COUT = 64, WT = 32, HT = 4, COT = 32, CK = 8;
  __shared__ float xs[CK][HT + 2][WT + 3];
  __shared__ float wl[CK][9][COT];

  int bx = blockIdx.x;
  int tw = bx & 7;
  int th = (bx >> 3) & 63;
  int b = bx >> 9;
  int coB = blockIdx.y * COT;
  int tid = threadIdx.x;
  int co4 = (tid & 7) * 4;
  int wq = ((tid >> 3) & 7) * 4;
  int hl = tid >> 6;
  int h0 = th * HT, w0 = tw * WT;

  float acc[4][4];
#pragma unroll
  for (int i = 0; i < 4; ++i)
#pragma unroll
    for (int j = 0; j < 4; ++j) acc[i][j] = 0.f;

  int nck = (CIN + CK - 1) / CK;
  for (int chb = 0; chb < nck; ++chb) {
    int cbase = chb * CK;
    int ck = CIN - cbase;
    if (ck > CK) ck = CK;
    __syncthreads();
    for (int i = tid; i < ck * (HT + 2) * (WT + 2); i += 256) {
      int c = i / ((HT + 2) * (WT + 2));
      int rem = i - c * ((HT + 2) * (WT + 2));
      int r = rem / (WT + 2), cc = rem - r * (WT + 2);
      int hh = h0 + r - 1, ww = w0 + cc - 1;
      float v = 0.f;
      if ((unsigned)hh < 256u && (unsigned)ww < 256u)
        v = x[((size_t)(b * CIN + cbase + c) << 16) + (hh << 8) + ww];
      xs[c][r][cc] = v;
    }
    for (int i = tid; i < ck * 9 * COT; i += 256) {
      int c = i / (9 * COT);
      int rem = i - c * (9 * COT);
      int tap = rem / COT, co = rem - tap * COT;
      wl[c][tap][co] = wT[((size_t)(cbase + c) * 9 + tap) * COUT + coB + co];
    }
    __syncthreads();
    for (int c = 0; c < ck; ++c) {
      float r0[6], r1[6], r2[6];
#pragma unroll
      for (int j = 0; j < 6; ++j) {
        r0[j] = xs[c][hl + 0][wq + j];
        r1[j] = xs[c][hl + 1][wq + j];
        r2[j] = xs[c][hl + 2][wq + j];
      }
#pragma unroll
      for (int tap = 0; tap < 9; ++tap) {
        int dy = tap / 3, dx = tap - dy * 3;
        float4 wv = *(const float4*)&wl[c][tap][co4];
#pragma unroll
        for (int wi = 0; wi < 4; ++wi) {
          float xv = (dy == 0 ? r0 : (dy == 1 ? r1 : r2))[dx + wi];
          acc[0][wi] += wv.x * xv;
          acc[1][wi] += wv.y * xv;
          acc[2][wi] += wv.z * xv;
          acc[3][wi] += wv.w * xv;
        }
      }
    }
  }
  float sv[4], tv[4];
#pragma unroll
  for (int ci = 0; ci < 4; ++ci) {
    sv[ci] = scale[coB + co4 + ci];
    tv[ci] = shift[coB + co4 + ci];
  }
#pragma unroll
  for (int wi = 0; wi < 4; ++wi) {
    f16x4 o;
#pragma unroll
    for (int ci = 0; ci < 4; ++ci)
      o[ci] = (f16)fmaxf(acc[ci][wi] * sv[ci] + tv[ci], 0.f);
    *(f16x4*)&y[((size_t)(b * 258 + h0 + hl + 1) * 258 + (w0 + wq + wi + 1)) * 64 +
                coB + co4] = o;
  }
}

// ---- MFMA conv: CIN=64 (+one-hot), COUT = NCS*32, padded NHWC fp16 ----
// Block: 128 threads = 2 waves (co-halves); 64-px row tile; 4-slot LDS row ring.
template <int NCS, int NS, bool ONEHOT, bool OUTPAD>
__global__ __launch_bounds__(128, 2) void k_convM(
    const f16* __restrict__ x, const f16* __restrict__ Wp,
    const float* __restrict__ scale, const float* __restrict__ shift,
    const float* __restrict__ fire, f16* __restrict__ y, int R) {
  constexpr int COUT = NCS * 32;
  constexpr int KT = NS * 32;
  __shared__ f16 xs[4][66 * 64];
  __shared__ unsigned char idxr[4][ONEHOT ? 68 : 4];
  __shared__ float sst[2][64];

  int tid = threadIdx.x;
  int lane = tid & 63;
  int l15 = lane & 15;
  int g = lane >> 4;
  int wco = tid >> 6;

  int strips = 256 / R;
  int per_b = 4 * strips;
  int bx = blockIdx.x;
  int b = bx / per_b;
  int rem = bx - b * per_b;
  int w0 = (rem & 3) * 64;
  int h0 = (rem >> 2) * R;

  // weights -> registers (A fragments)
  f16x8 Af[NCS][NS];
  {
    const f16* wb = Wp + (size_t)(wco * NCS * 16 + l15) * KT + g * 8;
#pragma unroll
    for (int cs = 0; cs < NCS; ++cs)
#pragma unroll
      for (int s = 0; s < NS; ++s)
        Af[cs][s] = *(const f16x8*)(wb + cs * 16 * KT + s * 32);
  }
  if (tid < COUT) {
    sst[0][tid] = scale[tid];
    sst[1][tid] = shift[tid];
  }

  auto stage_row = [&](int row) {
    const f16* src = x + ((size_t)(b * 258 + row + 1) * 258 + w0) * 64;
    f16* dst = &xs[row & 3][0];
    for (int c = tid; c < 528; c += 128) {
      int px = c >> 3, cc = c & 7;
      GLDS16(src + px * 64 + ((cc ^ (px & 7)) << 3), dst + c * 8);
    }
  };
  auto stage_idx = [&](int row) {
    if (ONEHOT && tid < 66) {
      int w = w0 - 1 + tid;
      int v = 4;  // border: matches no class -> zero one-hot
      if ((unsigned)row < 256u && (unsigned)w < 256u) {
        float f = fire[(b << 16) + (row << 8) + w];
        v = f < 0.25f ? 0 : (f < 0.75f ? 1 : 2);
      }
      idxr[row & 3][tid] = (unsigned char)v;
    }
  };

  stage_row(h0 - 1);
  stage_row(h0);
  stage_row(h0 + 1);
  stage_idx(h0 - 1);
  stage_idx(h0);
  stage_idx(h0 + 1);
  __syncthreads();

  for (int rr = 0; rr < R; ++rr) {
    int h = h0 + rr;
    if (h + 2 <= 256) stage_row(h + 2);
    stage_idx(h + 2);

    f32x4 acc[NCS][4];
#pragma unroll
    for (int cs = 0; cs < NCS; ++cs)
#pragma unroll
      for (int p = 0; p < 4; ++p) acc[cs][p] = (f32x4){0.f, 0.f, 0.f, 0.f};

    const f16* sp0 = &xs[(h - 1) & 3][0];
    const f16* sp1 = &xs[h & 3][0];
    const f16* sp2 = &xs[(h + 1) & 3][0];
#pragma unroll
    for (int tap = 0; tap < 9; ++tap) {
      const int dy = tap / 3, dx = tap - 3 * (tap / 3);
      const f16* sp = (dy == 0) ? sp0 : ((dy == 1) ? sp1 : sp2);
#pragma unroll
      for (int pxb = 0; pxb < 4; ++pxb) {
        int pxd = pxb * 16 + l15 + dx;
        int e0 = pxd * 64 + ((g ^ (pxd & 7)) << 3);
        f16x8 b0 = *(const f16x8*)(sp + e0);
        f16x8 b1 = *(const f16x8*)(sp + (e0 ^ 32));
#pragma unroll
        for (int cs = 0; cs < NCS; ++cs) {
          acc[cs][pxb] = __builtin_amdgcn_mfma_f32_16x16x32_f16(
              Af[cs][2 * tap], b0, acc[cs][pxb], 0, 0, 0);
          acc[cs][pxb] = __builtin_amdgcn_mfma_f32_16x16x32_f16(
              Af[cs][2 * tap + 1], b1, acc[cs][pxb], 0, 0, 0);
        }
      }
    }
    if (ONEHOT) {
      int ta = 2 * g, tb = ta + 1;
      int dya = ta / 3, dxa = ta - 3 * dya;
      int dyb = tb / 3, dxb = tb - 3 * dyb;
#pragma unroll
      for (int pxb = 0; pxb < 4; ++pxb) {
        int pxa = pxb * 16 + l15;
        unsigned ia = idxr[(h - 1 + dya) & 3][pxa + dxa];
        unsigned ib = idxr[(h - 1 + dyb) & 3][pxa + dxb];
        unsigned ic = idxr[(h + 1) & 3][pxa + 2];
        f16x8 b18, b19;
#pragma unroll
        for (int j = 0; j < 4; ++j) {
          b18[j] = (f16)((ia == (unsigned)j) ? 1.f : 0.f);
          b18[j + 4] = (f16)((ib == (unsigned)j) ? 1.f : 0.f);
          b19[j] = (f16)((g == 0 && ic == (unsigned)j) ? 1.f : 0.f);
          b19[j + 4] = (f16)0.f;
        }
#pragma unroll
        for (int cs = 0; cs < NCS; ++cs) {
          acc[cs][pxb] = __builtin_amdgcn_mfma_f32_16x16x32_f16(
              Af[cs][NS - 2], b18, acc[cs][pxb], 0, 0, 0);
          acc[cs][pxb] = __builtin_amdgcn_mfma_f32_16x16x32_f16(
              Af[cs][NS - 1], b19, acc[cs][pxb], 0, 0, 0);
        }
      }
    }
    // epilogue: BN scale/shift + relu, fp16 store
#pragma unroll
    for (int cs = 0; cs < NCS; ++cs) {
      int cb = wco * NCS * 16 + cs * 16 + 4 * g;
      f32x4 sv = *(const f32x4*)&sst[0][cb];
      f32x4 tv = *(const f32x4*)&sst[1][cb];
#pragma unroll
      for (int pxb = 0; pxb < 4; ++pxb) {
        int px = pxb * 16 + l15;
        f16x4 o;
#pragma unroll
        for (int r = 0; r < 4; ++r)
          o[r] = (f16)fmaxf(acc[cs][pxb][r] * sv[r] + tv[r], 0.f);
        size_t oi =
            OUTPAD ? ((size_t)(b * 258 + h + 1) * 258 + (w0 + px + 1)) * 64 + cb
                   : ((size_t)(b * 256 + h) * 256 + (w0 + px)) * 32 + cb;
        *(f16x4*)&y[oi] = o;
      }
    }
    __syncthreads();
  }
}

// ---- fused 1x1 conv (32->4) + softmax + wind conv + fire update ----
__global__ __launch_bounds__(256) void k_step(
    const f16* __restrict__ h2, const float* __restrict__ cw3,
    const float* __restrict__ cb3, const float* __restrict__ wke,
    const float* __restrict__ fin, float* __restrict__ fout,
    float* __restrict__ fout2) {
  __shared__ float wl[4][32];
  __shared__ float bl[4];
  __shared__ float wk[9];
  int tid = threadIdx.x;
  if (tid < 128) wl[tid >> 5][tid & 31] = cw3[tid];
  if (tid < 4) bl[tid] = cb3[tid];
  int bx = blockIdx.x;
  int b = bx >> 8, h = bx & 255;
  if (tid < 9) wk[tid] = wke[b * 9 + tid];
  __syncthreads();
  int w = tid;
  const f16* hp = h2 + ((size_t)(b * 256 + h) * 256 + w) * 32;
  float l0 = bl[0], l1 = bl[1], l2 = bl[2], l3 = bl[3];
#pragma unroll
  for (int c = 0; c < 32; ++c) {
    float v = (float)hp[c];
    l0 += v * wl[0][c];
    l1 += v * wl[1][c];
    l2 += v * wl[2][c];
    l3 += v * wl[3][c];
  }
  float mx = fmaxf(fmaxf(l0, l1), fmaxf(l2, l3));
  float e0 = expf(l0 - mx), e1 = expf(l1 - mx), e2 = expf(l2 - mx), e3 = expf(l3 - mx);
  float inv = 1.f / (e0 + e1 + e2 + e3);
  float p1 = e1 * inv, p2 = e2 * inv;
  const float* fp = fin + ((size_t)b << 16);
  float wacc = 0.f;
#pragma unroll
  for (int tap = 0; tap < 9; ++tap) {
    int dy = tap / 3 - 1, dx = tap % 3 - 1;
    int hh = h + dy, ww2 = w + dx;
    float f = ((unsigned)hh < 256u && (unsigned)ww2 < 256u) ? fp[(hh << 8) + ww2] : 0.f;
    wacc += wk[tap] * f;
  }
  float boost = 0.3f / (1.f + expf(-wacc));
  float fcur = fp[(h << 8) + w];
  float target = 0.5f * p1 + 0.5f * boost + p2;
  float fn = 0.7f * fcur + 0.3f * target;
  fn = fminf(fmaxf(fn, 0.f), 1.f);
  size_t o = ((size_t)b << 16) + (h << 8) + w;
  fout[o] = fn;
  if (fout2) fout2[o] = fn;
}

extern "C" void kernel_launch(void* const* d_in, const int* in_sizes, int n_in,
                              void* d_out, int out_size, void* d_ws, size_t ws_size,
                              hipStream_t stream) {
  const float* env = (const float*)d_in[0];
  const float* fire0 = (const float*)d_in[1];
  const float* w1 = (const float*)d_in[2];
  const float* b1 = (const float*)d_in[3];
  const float* g1 = (const float*)d_in[4];
  const float* be1 = (const float*)d_in[5];
  const float* m1 = (const float*)d_in[6];
  const float* v1 = (const float*)d_in[7];
  const float* w2 = (const float*)d_in[8];
  const float* b2 = (const float*)d_in[9];
  const float* g2 = (const float*)d_in[10];
  const float* be2 = (const float*)d_in[11];
  const float* m2 = (const float*)d_in[12];
  const float* v2 = (const float*)d_in[13];
  const float* cw1 = (const float*)d_in[14];
  const float* cb1 = (const float*)d_in[15];
  const float* cg1 = (const float*)d_in[16];
  const float* cbe1 = (const float*)d_in[17];
  const float* cm1 = (const float*)d_in[18];
  const float* cv1 = (const float*)d_in[19];
  const float* cw2 = (const float*)d_in[20];
  const float* cb2 = (const float*)d_in[21];
  const float* cg2 = (const float*)d_in[22];
  const float* cbe2 = (const float*)d_in[23];
  const float* cm2 = (const float*)d_in[24];
  const float* cv2 = (const float*)d_in[25];
  const float* cw3 = (const float*)d_in[26];
  const float* cb3 = (const float*)d_in[27];
  const float* windk = (const float*)d_in[28];
  // d_in[29] = num_steps (fixed 5)

  float* out = (float*)d_out;
  float* evo = out + 1048576;  // [6][16][1][256][256] fp32

  // ---- workspace layout ----
  uint8_t* p = (uint8_t*)d_ws;
  float* W1t = (float*)p;       p += 22 * 9 * 64 * 4;    // 50688
  f16* W2p = (f16*)p;           p += 64 * 576 * 2;       // 73728
  f16* Wc1p = (f16*)p;          p += 64 * 640 * 2;       // 81920
  f16* Wc2p = (f16*)p;          p += 32 * 576 * 2;       // 36864
  float* s1 = (float*)p;        p += 64 * 4;
  float* t1 = (float*)p;        p += 64 * 4;
  float* s2 = (float*)p;        p += 64 * 4;
  float* t2 = (float*)p;        p += 64 * 4;
  float* sc1 = (float*)p;       p += 64 * 4;
  float* tc1 = (float*)p;       p += 64 * 4;
  float* sc2 = (float*)p;       p += 64 * 4;
  float* tc2 = (float*)p;       p += 64 * 4;
  float* wke = (float*)p;       p += 1024;               // 16*9 f32 + pad
  const size_t IMGP = (size_t)258 * 258 * 64;            // padded elems/img
  const size_t ENVF_BYTES = 16 * IMGP * 2;               // 136.3 MB
  f16* envf = (f16*)p;          p += ENVF_BYTES;
  size_t fixed = (size_t)(p - (uint8_t*)d_ws);
  int NB = 1;
  for (int nb = 16; nb >= 1; nb >>= 1) {
    size_t need = fixed + (size_t)nb * (IMGP * 2 + (size_t)256 * 256 * 32 * 2);
    if (need <= ws_size) { NB = nb; break; }
  }
  f16* h1p = (f16*)p;           p += (size_t)NB * IMGP * 2;
  f16* h2 = (f16*)p;

  // ---- setup ----
  hipMemsetAsync(envf, 0, ENVF_BYTES, stream);
  hipMemsetAsync(h1p, 0, (size_t)NB * IMGP * 2, stream);
  k_wtrans<<<(64 * 22 * 9 + 255) / 256, 256, 0, stream>>>(w1, W1t, 64, 22);
  k_wprep64<<<(64 * 576 + 255) / 256, 256, 0, stream>>>(w2, W2p, 64);
  k_wprepC1<<<(64 * 640 + 255) / 256, 256, 0, stream>>>(cw1, Wc1p);
  k_wprep64<<<(32 * 576 + 255) / 256, 256, 0, stream>>>(cw2, Wc2p, 32);
  k_bnfuse<<<1, 256, 0, stream>>>(g1, be1, m1, v1, b1, s1, t1, 64);
  k_bnfuse<<<1, 256, 0, stream>>>(g2, be2, m2, v2, b2, s2, t2, 64);
  k_bnfuse<<<1, 256, 0, stream>>>(cg1, cbe1, cm1, cv1, cb1, sc1, tc1, 64);
  k_bnfuse<<<1, 256, 0, stream>>>(cg2, cbe2, cm2, cv2, cb2, sc2, tc2, 32);
  k_windgate<<<16, 256, 0, stream>>>(env, windk, wke);
  k_copy<<<1024, 256, 0, stream>>>(fire0, evo);

  const int R = 8;
  const int gconv = 4 * (256 / R);  // blocks per image

  // encoder (chunked)
  for (int b0 = 0; b0 < 16; b0 += NB) {
    k_conv1<<<dim3(NB * 512, 2), 256, 0, stream>>>(
        env + (size_t)b0 * 22 * HWSZ, W1t, s1, t1, h1p);
    k_convM<2, 18, false, true><<<NB * gconv, 128, 0, stream>>>(
        h1p, W2p, s2, t2, nullptr, envf + (size_t)b0 * IMGP, R);
  }
  // CA steps (chunked)
  for (int t = 0; t < 5; ++t) {
    const float* fin = evo + (size_t)t * 1048576;
    float* fo = evo + (size_t)(t + 1) * 1048576;
    for (int b0 = 0; b0 < 16; b0 += NB) {
      k_convM<2, 20, true, true><<<NB * gconv, 128, 0, stream>>>(
          envf + (size_t)b0 * IMGP, Wc1p, sc1, tc1, fin + (size_t)b0 * HWSZ, h1p, R);
      k_convM<1, 18, false, false><<<NB * gconv, 128, 0, stream>>>(
          h1p, Wc2p, sc2, tc2, nullptr, h2, R);
      k_step<<<NB * 256, 256, 0, stream>>>(
          h2, cw3, cb3, wke + (size_t)b0 * 9, fin + (size_t)b0 * HWSZ,
          fo + (size_t)b0 * HWSZ, (t == 4) ? out + (size_t)b0 * HWSZ : nullptr);
    }
  }
}

// Round 4
// 1436.888 us; speedup vs baseline: 8.2004x; 1.1435x over previous
//
#include <hip/hip_runtime.h>
#include <cstdint>
#include <cstddef>

// LearnableCA fire-spread, round 4: ALL convs on fp16 MFMA.
// conv1 (22->64) now implicit-GEMM: env converted to padded NHWC fp16 with
// ch7 pre-scaled 1/64 (weights x64). Border-zero kernel replaces memsets.
// Activations: padded NHWC fp16 [b][258][258][C]; K-order k = tap*CIN + ci.

#define HWSZ 65536

typedef _Float16 f16;
typedef f16 f16x8 __attribute__((ext_vector_type(8)));
typedef f16 f16x4 __attribute__((ext_vector_type(4)));
typedef float f32x4 __attribute__((ext_vector_type(4)));

#define GLDS16(gp, lp)                                                        \
  __builtin_amdgcn_global_load_lds(                                           \
      (const __attribute__((address_space(1))) void*)(gp),                    \
      (__attribute__((address_space(3))) void*)(lp), 16, 0, 0)

// ---- conv1 weight prep: [64][22][3][3] -> [co][tap*32+ci], ci7 x64, pad->32 ----
__global__ void k_wprepC0(const float* __restrict__ src, f16* __restrict__ dst) {
  int i = blockIdx.x * 256 + threadIdx.x;
  if (i >= 64 * 288) return;
  int co = i / 288, k = i - co * 288;
  int tap = k >> 5, ci = k & 31;
  float v = 0.f;
  if (ci < 22) {
    v = src[(co * 22 + ci) * 9 + tap];
    if (ci == 7) v *= 64.f;
  }
  dst[i] = (f16)v;
}

// ---- fp16 weight prep: [co][ci 64][3][3] -> [co][tap*64+ci] ----
__global__ void k_wprep64(const float* __restrict__ src, f16* __restrict__ dst,
                          int COUT) {
  int i = blockIdx.x * 256 + threadIdx.x;
  if (i >= COUT * 576) return;
  int co = i / 576, k = i - co * 576;
  int tap = k >> 6, ci = k & 63;
  dst[i] = (f16)src[(co * 64 + ci) * 9 + tap];
}

// ---- cw1 prep: 64 normal ci + one-hot block (kl = tap*4+oc) -> [co][640] ----
__global__ void k_wprepC1(const float* __restrict__ src, f16* __restrict__ dst) {
  int i = blockIdx.x * 256 + threadIdx.x;
  if (i >= 64 * 640) return;
  int co = i / 640, k = i - co * 640;
  float v;
  if (k < 576) {
    int tap = k >> 6, ci = k & 63;
    v = src[(co * 68 + ci) * 9 + tap];
  } else {
    int kl = k - 576;
    int oc = kl & 3, tp = kl >> 2;
    v = (tp < 9) ? src[(co * 68 + 64 + oc) * 9 + tp] : 0.f;
  }
  dst[i] = (f16)v;
}

// ---- fold BN + conv bias into per-channel scale/shift ----
__global__ void k_bnfuse(const float* __restrict__ g, const float* __restrict__ be,
                         const float* __restrict__ m, const float* __restrict__ v,
                         const float* __restrict__ bc, float* __restrict__ s,
                         float* __restrict__ t, int C) {
  int c = threadIdx.x;
  if (c < C) {
    float sc = g[c] * rsqrtf(v[c] + 1e-5f);
    s[c] = sc;
    t[c] = (bc[c] - m[c]) * sc + be[c];
  }
}

// ---- per-batch wind gate ----
__global__ void k_windgate(const float* __restrict__ env, const float* __restrict__ wind_k,
                           float* __restrict__ wke) {
  int b = blockIdx.x;
  const float* a7 = env + (((size_t)(b * 22 + 7)) << 16);
  const float* a8 = env + (((size_t)(b * 22 + 8)) << 16);
  double s7 = 0.0, s8 = 0.0;
  for (int i = threadIdx.x; i < HWSZ; i += 256) { s7 += a7[i]; s8 += a8[i]; }
  __shared__ double r7[256], r8[256];
  r7[threadIdx.x] = s7; r8[threadIdx.x] = s8;
  __syncthreads();
  for (int off = 128; off > 0; off >>= 1) {
    if (threadIdx.x < off) {
      r7[threadIdx.x] += r7[threadIdx.x + off];
      r8[threadIdx.x] += r8[threadIdx.x + off];
    }
    __syncthreads();
  }
  if (threadIdx.x == 0) {
    float wa = (float)(r7[0] * (1.0 / 65536.0));
    float wsp = (float)(r8[0] * (1.0 / 65536.0));
    float wsc = fminf(fmaxf(wsp * (1.f / 20.f), 0.f), 1.f);
    float wk[9];
#pragma unroll
    for (int tp = 0; tp < 9; ++tp) wk[tp] = 0.f;
    for (int d = 0; d < 8; ++d) {
      float diff = fabsf(wa - 45.f * (float)d);
      diff = fminf(diff, 360.f - diff);
      float dw = fmaxf(0.f, 1.f - diff * (1.f / 90.f));
      float eff = (dw > 0.1f && wsc > 0.1f) ? dw * wsc : 0.f;
      for (int tp = 0; tp < 9; ++tp) wk[tp] += eff * wind_k[d * 9 + tp];
    }
    for (int tp = 0; tp < 9; ++tp) wke[b * 9 + tp] = wk[tp];
  }
}

__global__ void k_copy(const float* __restrict__ src, float* __restrict__ dst) {
  int i = blockIdx.x * 256 + threadIdx.x;
  ((float4*)dst)[i] = ((const float4*)src)[i];
}

// ---- zero the 1-px border of a padded NHWC buffer [n][258][258][C] ----
__global__ void k_border(f16* __restrict__ buf, int nimg, int C) {
  int i = blockIdx.x * 256 + threadIdx.x;
  int per = 1028 * C;
  if (i >= nimg * per) return;
  int img = i / per, r = i - img * per;
  int px = r / C, c = r - px * C;
  int h, w;
  if (px < 258) { h = 0; w = px; }
  else if (px < 516) { h = 257; w = px - 258; }
  else if (px < 772) { h = px - 515; w = 0; }
  else { h = px - 771; w = 257; }
  buf[((size_t)(img * 258 + h) * 258 + w) * C + c] = (f16)0.f;
}

// ---- env NCHW fp32 -> padded NHWC fp16 [258][258][32], ch7 * 1/64 ----
__global__ __launch_bounds__(256) void k_env2h(const float* __restrict__ env,
                                               f16* __restrict__ dst, int nimg) {
  int i = blockIdx.x * 256 + threadIdx.x;
  if (i >= (nimg << 16)) return;
  int b = i >> 16, hw = i & 65535;
  int h = hw >> 8, w = hw & 255;
  const float* sp = env + (((size_t)b * 22) << 16) + hw;
  f16 o[32];
#pragma unroll
  for (int c = 0; c < 22; ++c) {
    float v = sp[(size_t)c << 16];
    if (c == 7) v *= (1.f / 64.f);
    o[c] = (f16)v;
  }
#pragma unroll
  for (int c = 22; c < 32; ++c) o[c] = (f16)0.f;
  f16* dp = dst + ((size_t)(b * 258 + h + 1) * 258 + (w + 1)) * 32;
  *(f16x8*)(dp + 0) = *(f16x8*)&o[0];
  *(f16x8*)(dp + 8) = *(f16x8*)&o[8];
  *(f16x8*)(dp + 16) = *(f16x8*)&o[16];
  *(f16x8*)(dp + 24) = *(f16x8*)&o[24];
}

// ---- MFMA conv: CIN in {32,64} (+one-hot), COUT = NCS*32, padded NHWC ----
// Block: 128 threads = 2 waves (co-halves); 64-px row tile; 4-slot LDS row ring.
template <int CIN, int NCS, int NS, bool ONEHOT, bool OUTPAD>
__global__ __launch_bounds__(128, 2) void k_convM(
    const f16* __restrict__ x, const f16* __restrict__ Wp,
    const float* __restrict__ scale, const float* __restrict__ shift,
    const float* __restrict__ fire, f16* __restrict__ y, int R) {
  constexpr int COUT = NCS * 32;
  constexpr int KT = NS * 32;
  constexpr int CC = CIN / 8;  // f16x8 chunks per px
  __shared__ f16 xs[4][66 * CIN];
  __shared__ unsigned char idxr[4][ONEHOT ? 68 : 4];
  __shared__ float sst[2][64];

  int tid = threadIdx.x;
  int lane = tid & 63;
  int l15 = lane & 15;
  int g = lane >> 4;
  int wco = tid >> 6;

  int strips = 256 / R;
  int per_b = 4 * strips;
  int bx = blockIdx.x;
  int b = bx / per_b;
  int rem = bx - b * per_b;
  int w0 = (rem & 3) * 64;
  int h0 = (rem >> 2) * R;

  // weights -> registers (A fragments)
  f16x8 Af[NCS][NS];
  {
    const f16* wb = Wp + (size_t)(wco * NCS * 16 + l15) * KT + g * 8;
#pragma unroll
    for (int cs = 0; cs < NCS; ++cs)
#pragma unroll
      for (int s = 0; s < NS; ++s)
        Af[cs][s] = *(const f16x8*)(wb + cs * 16 * KT + s * 32);
  }
  if (tid < COUT) {
    sst[0][tid] = scale[tid];
    sst[1][tid] = shift[tid];
  }

  auto swz = [&](int px) { return CIN == 64 ? (px & 7) : ((px >> 1) & 3); };

  auto stage_row = [&](int row) {
    const f16* src = x + ((size_t)(b * 258 + row + 1) * 258 + w0) * CIN;
    f16* dst = &xs[row & 3][0];
    for (int c = tid; c < 66 * CC; c += 128) {
      int px = c / CC, cc = c - px * CC;
      GLDS16(src + px * CIN + ((cc ^ swz(px)) << 3), dst + c * 8);
    }
  };
  auto stage_idx = [&](int row) {
    if (ONEHOT && tid < 66) {
      int w = w0 - 1 + tid;
      int v = 4;  // border: matches no class -> zero one-hot
      if ((unsigned)row < 256u && (unsigned)w < 256u) {
        float f = fire[(b << 16) + (row << 8) + w];
        v = f < 0.25f ? 0 : (f < 0.75f ? 1 : 2);
      }
      idxr[row & 3][tid] = (unsigned char)v;
    }
  };

  stage_row(h0 - 1);
  stage_row(h0);
  stage_row(h0 + 1);
  stage_idx(h0 - 1);
  stage_idx(h0);
  stage_idx(h0 + 1);
  __syncthreads();

  for (int rr = 0; rr < R; ++rr) {
    int h = h0 + rr;
    if (h + 2 <= 256) stage_row(h + 2);
    stage_idx(h + 2);

    f32x4 acc[NCS][4];
#pragma unroll
    for (int cs = 0; cs < NCS; ++cs)
#pragma unroll
      for (int p = 0; p < 4; ++p) acc[cs][p] = (f32x4){0.f, 0.f, 0.f, 0.f};

    const f16* sp0 = &xs[(h - 1) & 3][0];
    const f16* sp1 = &xs[h & 3][0];
    const f16* sp2 = &xs[(h + 1) & 3][0];
#pragma unroll
    for (int tap = 0; tap < 9; ++tap) {
      const int dy = tap / 3, dx = tap - 3 * (tap / 3);
      const f16* sp = (dy == 0) ? sp0 : ((dy == 1) ? sp1 : sp2);
#pragma unroll
      for (int pxb = 0; pxb < 4; ++pxb) {
        int pxd = pxb * 16 + l15 + dx;
        int sz = swz(pxd);
#pragma unroll
        for (int half = 0; half < CIN / 32; ++half) {
          f16x8 bb = *(const f16x8*)(sp + pxd * CIN + (((g + half * 4) ^ sz) << 3));
#pragma unroll
          for (int cs = 0; cs < NCS; ++cs)
            acc[cs][pxb] = __builtin_amdgcn_mfma_f32_16x16x32_f16(
                Af[cs][tap * (CIN / 32) + half], bb, acc[cs][pxb], 0, 0, 0);
        }
      }
    }
    if (ONEHOT) {
      int ta = 2 * g, tb = ta + 1;
      int dya = ta / 3, dxa = ta - 3 * dya;
      int dyb = tb / 3, dxb = tb - 3 * dyb;
#pragma unroll
      for (int pxb = 0; pxb < 4; ++pxb) {
        int pxa = pxb * 16 + l15;
        unsigned ia = idxr[(h - 1 + dya) & 3][pxa + dxa];
        unsigned ib = idxr[(h - 1 + dyb) & 3][pxa + dxb];
        unsigned ic = idxr[(h + 1) & 3][pxa + 2];
        f16x8 b18, b19;
#pragma unroll
        for (int j = 0; j < 4; ++j) {
          b18[j] = (f16)((ia == (unsigned)j) ? 1.f : 0.f);
          b18[j + 4] = (f16)((ib == (unsigned)j) ? 1.f : 0.f);
          b19[j] = (f16)((g == 0 && ic == (unsigned)j) ? 1.f : 0.f);
          b19[j + 4] = (f16)0.f;
        }
#pragma unroll
        for (int cs = 0; cs < NCS; ++cs) {
          acc[cs][pxb] = __builtin_amdgcn_mfma_f32_16x16x32_f16(
              Af[cs][NS - 2], b18, acc[cs][pxb], 0, 0, 0);
          acc[cs][pxb] = __builtin_amdgcn_mfma_f32_16x16x32_f16(
              Af[cs][NS - 1], b19, acc[cs][pxb], 0, 0, 0);
        }
      }
    }
    // epilogue: BN scale/shift + relu, fp16 store
#pragma unroll
    for (int cs = 0; cs < NCS; ++cs) {
      int cb = wco * NCS * 16 + cs * 16 + 4 * g;
      f32x4 sv = *(const f32x4*)&sst[0][cb];
      f32x4 tv = *(const f32x4*)&sst[1][cb];
#pragma unroll
      for (int pxb = 0; pxb < 4; ++pxb) {
        int px = pxb * 16 + l15;
        f16x4 o;
#pragma unroll
        for (int r = 0; r < 4; ++r)
          o[r] = (f16)fmaxf(acc[cs][pxb][r] * sv[r] + tv[r], 0.f);
        size_t oi =
            OUTPAD ? ((size_t)(b * 258 + h + 1) * 258 + (w0 + px + 1)) * 64 + cb
                   : ((size_t)(b * 256 + h) * 256 + (w0 + px)) * 32 + cb;
        *(f16x4*)&y[oi] = o;
      }
    }
    __syncthreads();
  }
}

// ---- fused 1x1 conv (32->4) + softmax + wind conv + fire update ----
__global__ __launch_bounds__(256) void k_step(
    const f16* __restrict__ h2, const float* __restrict__ cw3,
    const float* __restrict__ cb3, const float* __restrict__ wke,
    const float* __restrict__ fin, float* __restrict__ fout,
    float* __restrict__ fout2) {
  __shared__ float wl[4][32];
  __shared__ float bl[4];
  __shared__ float wk[9];
  int tid = threadIdx.x;
  if (tid < 128) wl[tid >> 5][tid & 31] = cw3[tid];
  if (tid < 4) bl[tid] = cb3[tid];
  int bx = blockIdx.x;
  int b = bx >> 8, h = bx & 255;
  if (tid < 9) wk[tid] = wke[b * 9 + tid];
  __syncthreads();
  int w = tid;
  const f16x8* hp8 = (const f16x8*)(h2 + ((size_t)(b * 256 + h) * 256 + w) * 32);
  float l0 = bl[0], l1 = bl[1], l2 = bl[2], l3 = bl[3];
#pragma unroll
  for (int q = 0; q < 4; ++q) {
    f16x8 v8 = hp8[q];
#pragma unroll
    for (int j = 0; j < 8; ++j) {
      float v = (float)v8[j];
      int c = q * 8 + j;
      l0 += v * wl[0][c];
      l1 += v * wl[1][c];
      l2 += v * wl[2][c];
      l3 += v * wl[3][c];
    }
  }
  float mx = fmaxf(fmaxf(l0, l1), fmaxf(l2, l3));
  float e0 = expf(l0 - mx), e1 = expf(l1 - mx), e2 = expf(l2 - mx), e3 = expf(l3 - mx);
  float inv = 1.f / (e0 + e1 + e2 + e3);
  float p1 = e1 * inv, p2 = e2 * inv;
  const float* fp = fin + ((size_t)b << 16);
  float wacc = 0.f;
#pragma unroll
  for (int tap = 0; tap < 9; ++tap) {
    int dy = tap / 3 - 1, dx = tap % 3 - 1;
    int hh = h + dy, ww2 = w + dx;
    float f = ((unsigned)hh < 256u && (unsigned)ww2 < 256u) ? fp[(hh << 8) + ww2] : 0.f;
    wacc += wk[tap] * f;
  }
  float boost = 0.3f / (1.f + expf(-wacc));
  float fcur = fp[(h << 8) + w];
  float target = 0.5f * p1 + 0.5f * boost + p2;
  float fn = 0.7f * fcur + 0.3f * target;
  fn = fminf(fmaxf(fn, 0.f), 1.f);
  size_t o = ((size_t)b << 16) + (h << 8) + w;
  fout[o] = fn;
  if (fout2) fout2[o] = fn;
}

extern "C" void kernel_launch(void* const* d_in, const int* in_sizes, int n_in,
                              void* d_out, int out_size, void* d_ws, size_t ws_size,
                              hipStream_t stream) {
  const float* env = (const float*)d_in[0];
  const float* fire0 = (const float*)d_in[1];
  const float* w1 = (const float*)d_in[2];
  const float* b1 = (const float*)d_in[3];
  const float* g1 = (const float*)d_in[4];
  const float* be1 = (const float*)d_in[5];
  const float* m1 = (const float*)d_in[6];
  const float* v1 = (const float*)d_in[7];
  const float* w2 = (const float*)d_in[8];
  const float* b2 = (const float*)d_in[9];
  const float* g2 = (const float*)d_in[10];
  const float* be2 = (const float*)d_in[11];
  const float* m2 = (const float*)d_in[12];
  const float* v2 = (const float*)d_in[13];
  const float* cw1 = (const float*)d_in[14];
  const float* cb1 = (const float*)d_in[15];
  const float* cg1 = (const float*)d_in[16];
  const float* cbe1 = (const float*)d_in[17];
  const float* cm1 = (const float*)d_in[18];
  const float* cv1 = (const float*)d_in[19];
  const float* cw2 = (const float*)d_in[20];
  const float* cb2 = (const float*)d_in[21];
  const float* cg2 = (const float*)d_in[22];
  const float* cbe2 = (const float*)d_in[23];
  const float* cm2 = (const float*)d_in[24];
  const float* cv2 = (const float*)d_in[25];
  const float* cw3 = (const float*)d_in[26];
  const float* cb3 = (const float*)d_in[27];
  const float* windk = (const float*)d_in[28];
  // d_in[29] = num_steps (fixed 5)

  float* out = (float*)d_out;
  float* evo = out + 1048576;  // [6][16][1][256][256] fp32

  // ---- workspace layout ----
  uint8_t* p = (uint8_t*)d_ws;
  f16* W1p = (f16*)p;           p += 64 * 288 * 2;       // 36864
  f16* W2p = (f16*)p;           p += 64 * 576 * 2;       // 73728
  f16* Wc1p = (f16*)p;          p += 64 * 640 * 2;       // 81920
  f16* Wc2p = (f16*)p;          p += 32 * 576 * 2;       // 36864
  float* s1 = (float*)p;        p += 64 * 4;
  float* t1 = (float*)p;        p += 64 * 4;
  float* s2 = (float*)p;        p += 64 * 4;
  float* t2 = (float*)p;        p += 64 * 4;
  float* sc1 = (float*)p;       p += 64 * 4;
  float* tc1 = (float*)p;       p += 64 * 4;
  float* sc2 = (float*)p;       p += 64 * 4;
  float* tc2 = (float*)p;       p += 64 * 4;
  float* wke = (float*)p;       p += 1024;               // 16*9 f32 + pad
  const size_t IMGP = (size_t)258 * 258 * 64;            // padded 64ch elems/img
  const size_t IMGP32 = (size_t)258 * 258 * 32;          // padded 32ch elems/img
  f16* envf = (f16*)p;          p += 16 * IMGP * 2;      // 136.3 MB
  size_t fixed = (size_t)(p - (uint8_t*)d_ws);
  int NB = 1;
  for (int nb = 16; nb >= 1; nb >>= 1) {
    size_t need = fixed + (size_t)nb * (IMGP * 2 + IMGP32 * 2);
    if (need <= ws_size) { NB = nb; break; }
  }
  f16* h1p = (f16*)p;           p += (size_t)NB * IMGP * 2;
  f16* envin = (f16*)p;  // NB*IMGP32, overlaid with h2 (time-disjoint)
  f16* h2 = envin;       // [NB][256][256][32] unpadded

  // ---- setup ----
  k_wprepC0<<<(64 * 288 + 255) / 256, 256, 0, stream>>>(w1, W1p);
  k_wprep64<<<(64 * 576 + 255) / 256, 256, 0, stream>>>(w2, W2p, 64);
  k_wprepC1<<<(64 * 640 + 255) / 256, 256, 0, stream>>>(cw1, Wc1p);
  k_wprep64<<<(32 * 576 + 255) / 256, 256, 0, stream>>>(cw2, Wc2p, 32);
  k_bnfuse<<<1, 256, 0, stream>>>(g1, be1, m1, v1, b1, s1, t1, 64);
  k_bnfuse<<<1, 256, 0, stream>>>(g2, be2, m2, v2, b2, s2, t2, 64);
  k_bnfuse<<<1, 256, 0, stream>>>(cg1, cbe1, cm1, cv1, cb1, sc1, tc1, 64);
  k_bnfuse<<<1, 256, 0, stream>>>(cg2, cbe2, cm2, cv2, cb2, sc2, tc2, 32);
  k_windgate<<<16, 256, 0, stream>>>(env, windk, wke);
  k_copy<<<1024, 256, 0, stream>>>(fire0, evo);
  k_border<<<(16 * 1028 * 64 + 255) / 256, 256, 0, stream>>>(envf, 16, 64);
  k_border<<<(NB * 1028 * 64 + 255) / 256, 256, 0, stream>>>(h1p, NB, 64);
  k_border<<<(NB * 1028 * 32 + 255) / 256, 256, 0, stream>>>(envin, NB, 32);

  const int R = 8;
  const int gconv = 4 * (256 / R);  // blocks per image

  // encoder (chunked)
  for (int b0 = 0; b0 < 16; b0 += NB) {
    k_env2h<<<NB * 256, 256, 0, stream>>>(env + (size_t)b0 * 22 * HWSZ, envin, NB);
    k_convM<32, 2, 9, false, true><<<NB * gconv, 128, 0, stream>>>(
        envin, W1p, s1, t1, nullptr, h1p, R);
    k_convM<64, 2, 18, false, true><<<NB * gconv, 128, 0, stream>>>(
        h1p, W2p, s2, t2, nullptr, envf + (size_t)b0 * IMGP, R);
  }
  // CA steps (chunked)
  for (int t = 0; t < 5; ++t) {
    const float* fin = evo + (size_t)t * 1048576;
    float* fo = evo + (size_t)(t + 1) * 1048576;
    for (int b0 = 0; b0 < 16; b0 += NB) {
      k_convM<64, 2, 20, true, true><<<NB * gconv, 128, 0, stream>>>(
          envf + (size_t)b0 * IMGP, Wc1p, sc1, tc1, fin + (size_t)b0 * HWSZ, h1p, R);
      k_convM<64, 1, 18, false, false><<<NB * gconv, 128, 0, stream>>>(
          h1p, Wc2p, sc2, tc2, nullptr, h2, R);
      k_step<<<NB * 256, 256, 0, stream>>>(
          h2, cw3, cb3, wke + (size_t)b0 * 9, fin + (size_t)b0 * HWSZ,
          fo + (size_t)b0 * HWSZ, (t == 4) ? out + (size_t)b0 * HWSZ : nullptr);
    }
  }
}

// Round 5
// 1232.799 us; speedup vs baseline: 9.5580x; 1.1655x over previous
//
#include <hip/hip_runtime.h>
#include <cstdint>
#include <cstddef>

// LearnableCA fire-spread, round 5: counted-vmcnt pipelined MFMA convs.
// - 2-row phases, 8-slot LDS row ring, 2-phase stage-ahead, raw s_barrier with
//   s_waitcnt vmcnt(N) (N = this phase's own stage instr count per wave).
// - width-32 tiles, R=32 rows/block, grid = NB*64 blocks, XCD band swizzle.
// - one-hot classes from precomputed padded uint8 fire map (k_firemap).
// - cw2 px-split (waves split pixels, each does all 32 couts): halves LDS reads.

#define HWSZ 65536

typedef _Float16 f16;
typedef f16 f16x8 __attribute__((ext_vector_type(8)));
typedef f16 f16x4 __attribute__((ext_vector_type(4)));
typedef float f32x4 __attribute__((ext_vector_type(4)));

#define GLDS16(gp, lp)                                                        \
  __builtin_amdgcn_global_load_lds(                                           \
      (const __attribute__((address_space(1))) void*)(gp),                    \
      (__attribute__((address_space(3))) void*)(lp), 16, 0, 0)

// ---- conv1 weight prep: [64][22][3][3] -> [co][tap*32+ci], ci7 x64, pad->32 ----
__global__ void k_wprepC0(const float* __restrict__ src, f16* __restrict__ dst) {
  int i = blockIdx.x * 256 + threadIdx.x;
  if (i >= 64 * 288) return;
  int co = i / 288, k = i - co * 288;
  int tap = k >> 5, ci = k & 31;
  float v = 0.f;
  if (ci < 22) {
    v = src[(co * 22 + ci) * 9 + tap];
    if (ci == 7) v *= 64.f;
  }
  dst[i] = (f16)v;
}

// ---- fp16 weight prep: [co][ci 64][3][3] -> [co][tap*64+ci] ----
__global__ void k_wprep64(const float* __restrict__ src, f16* __restrict__ dst,
                          int COUT) {
  int i = blockIdx.x * 256 + threadIdx.x;
  if (i >= COUT * 576) return;
  int co = i / 576, k = i - co * 576;
  int tap = k >> 6, ci = k & 63;
  dst[i] = (f16)src[(co * 64 + ci) * 9 + tap];
}

// ---- cw1 prep: 64 normal ci + one-hot block (kl = tap*4+oc) -> [co][640] ----
__global__ void k_wprepC1(const float* __restrict__ src, f16* __restrict__ dst) {
  int i = blockIdx.x * 256 + threadIdx.x;
  if (i >= 64 * 640) return;
  int co = i / 640, k = i - co * 640;
  float v;
  if (k < 576) {
    int tap = k >> 6, ci = k & 63;
    v = src[(co * 68 + ci) * 9 + tap];
  } else {
    int kl = k - 576;
    int oc = kl & 3, tp = kl >> 2;
    v = (tp < 9) ? src[(co * 68 + 64 + oc) * 9 + tp] : 0.f;
  }
  dst[i] = (f16)v;
}

// ---- fold BN + conv bias into per-channel scale/shift ----
__global__ void k_bnfuse(const float* __restrict__ g, const float* __restrict__ be,
                         const float* __restrict__ m, const float* __restrict__ v,
                         const float* __restrict__ bc, float* __restrict__ s,
                         float* __restrict__ t, int C) {
  int c = threadIdx.x;
  if (c < C) {
    float sc = g[c] * rsqrtf(v[c] + 1e-5f);
    s[c] = sc;
    t[c] = (bc[c] - m[c]) * sc + be[c];
  }
}

// ---- per-batch wind gate ----
__global__ void k_windgate(const float* __restrict__ env, const float* __restrict__ wind_k,
                           float* __restrict__ wke) {
  int b = blockIdx.x;
  const float* a7 = env + (((size_t)(b * 22 + 7)) << 16);
  const float* a8 = env + (((size_t)(b * 22 + 8)) << 16);
  double s7 = 0.0, s8 = 0.0;
  for (int i = threadIdx.x; i < HWSZ; i += 256) { s7 += a7[i]; s8 += a8[i]; }
  __shared__ double r7[256], r8[256];
  r7[threadIdx.x] = s7; r8[threadIdx.x] = s8;
  __syncthreads();
  for (int off = 128; off > 0; off >>= 1) {
    if (threadIdx.x < off) {
      r7[threadIdx.x] += r7[threadIdx.x + off];
      r8[threadIdx.x] += r8[threadIdx.x + off];
    }
    __syncthreads();
  }
  if (threadIdx.x == 0) {
    float wa = (float)(r7[0] * (1.0 / 65536.0));
    float wsp = (float)(r8[0] * (1.0 / 65536.0));
    float wsc = fminf(fmaxf(wsp * (1.f / 20.f), 0.f), 1.f);
    float wk[9];
#pragma unroll
    for (int tp = 0; tp < 9; ++tp) wk[tp] = 0.f;
    for (int d = 0; d < 8; ++d) {
      float diff = fabsf(wa - 45.f * (float)d);
      diff = fminf(diff, 360.f - diff);
      float dw = fmaxf(0.f, 1.f - diff * (1.f / 90.f));
      float eff = (dw > 0.1f && wsc > 0.1f) ? dw * wsc : 0.f;
      for (int tp = 0; tp < 9; ++tp) wk[tp] += eff * wind_k[d * 9 + tp];
    }
    for (int tp = 0; tp < 9; ++tp) wke[b * 9 + tp] = wk[tp];
  }
}

__global__ void k_copy(const float* __restrict__ src, float* __restrict__ dst) {
  int i = blockIdx.x * 256 + threadIdx.x;
  ((float4*)dst)[i] = ((const float4*)src)[i];
}

// ---- zero the 1-px border of a padded NHWC buffer [n][258][258][C] ----
__global__ void k_border(f16* __restrict__ buf, int nimg, int C) {
  int i = blockIdx.x * 256 + threadIdx.x;
  int per = 1028 * C;
  if (i >= nimg * per) return;
  int img = i / per, r = i - img * per;
  int px = r / C, c = r - px * C;
  int h, w;
  if (px < 258) { h = 0; w = px; }
  else if (px < 516) { h = 257; w = px - 258; }
  else if (px < 772) { h = px - 515; w = 0; }
  else { h = px - 771; w = 257; }
  buf[((size_t)(img * 258 + h) * 258 + w) * C + c] = (f16)0.f;
}

// ---- env NCHW fp32 -> padded NHWC fp16 [258][258][32], ch7 * 1/64 ----
__global__ __launch_bounds__(256) void k_env2h(const float* __restrict__ env,
                                               f16* __restrict__ dst, int nimg) {
  int i = blockIdx.x * 256 + threadIdx.x;
  if (i >= (nimg << 16)) return;
  int b = i >> 16, hw = i & 65535;
  int h = hw >> 8, w = hw & 255;
  const float* sp = env + (((size_t)b * 22) << 16) + hw;
  f16 o[32];
#pragma unroll
  for (int c = 0; c < 22; ++c) {
    float v = sp[(size_t)c << 16];
    if (c == 7) v *= (1.f / 64.f);
    o[c] = (f16)v;
  }
#pragma unroll
  for (int c = 22; c < 32; ++c) o[c] = (f16)0.f;
  f16* dp = dst + ((size_t)(b * 258 + h + 1) * 258 + (w + 1)) * 32;
  *(f16x8*)(dp + 0) = *(f16x8*)&o[0];
  *(f16x8*)(dp + 8) = *(f16x8*)&o[8];
  *(f16x8*)(dp + 16) = *(f16x8*)&o[16];
  *(f16x8*)(dp + 24) = *(f16x8*)&o[24];
}

// ---- padded uint8 fire-class map: [b][258][258], border=4 ----
__global__ void k_firemap(const float* __restrict__ fire, unsigned char* __restrict__ map,
                          int nimg) {
  int i = blockIdx.x * 256 + threadIdx.x;
  if (i >= nimg * 66564) return;
  int b = i / 66564, r = i - b * 66564;
  int h = r / 258, w = r - h * 258;
  unsigned char v = 4;
  if (h >= 1 && h <= 256 && w >= 1 && w <= 256) {
    float f = fire[((size_t)b << 16) + ((h - 1) << 8) + (w - 1)];
    v = f < 0.25f ? 0 : (f < 0.75f ? 1 : 2);
  }
  map[i] = v;
}

// ---- MFMA conv, pipelined: CIN in {32,64}, width-32 tile, R=32 rows/block ----
// 128 threads = 2 waves. PXSPLIT=false: waves split couts (COUT=NCS*32);
// PXSPLIT=true: waves split pixels, each does all COUT=NCS*16 couts.
template <int CIN, int NCS, int NS, bool ONEHOT, bool OUTPAD, bool PXSPLIT, int MINW>
__global__ __launch_bounds__(128, MINW) void k_convM(
    const f16* __restrict__ x, const f16* __restrict__ Wp,
    const float* __restrict__ scale, const float* __restrict__ shift,
    const unsigned char* __restrict__ fmap, f16* __restrict__ y, int NB) {
  constexpr int COUT = PXSPLIT ? NCS * 16 : NCS * 32;
  constexpr int KT = NS * 32;
  constexpr int CC = CIN / 8;           // 16B chunks per px
  constexpr int PERROW = 34 * CC;       // 16B chunks per staged row
  constexpr int ROWE = 34 * CIN;        // f16 per row slot
  constexpr int PXW = PXSPLIT ? 1 : 2;  // px-frag groups per wave
  constexpr int NH = CIN / 32;          // k-halves per tap
  // stage instr counts per wave per 2-row phase (wave0 gets the ragged tail)
  constexpr int VN0 = (CIN == 64) ? 6 : 4;
  constexpr int VN1 = (CIN == 64) ? 4 : 2;

  __shared__ __align__(16) f16 xs[8][ROWE];
  __shared__ float sst[2][COUT];

  int tid = threadIdx.x;
  int lane = tid & 63;
  int l15 = lane & 15;
  int g = (lane >> 4) & 3;
  int wco = tid >> 6;

  // block decode with XCD band grouping: d%8 = hs constant per band
  int d = blockIdx.x;
  int hsn = NB * 8;
  int ws = d / hsn;
  int t = d - ws * hsn;
  int b = t >> 3;
  int hs = t & 7;
  int w0 = ws * 32, h0 = hs * 32;

  int co_base = PXSPLIT ? 0 : wco * NCS * 16;
  int pxg = PXSPLIT ? wco * 16 : 0;

  // weights -> registers/AGPRs
  f16x8 Af[NCS][NS];
  {
    const f16* wb = Wp + (size_t)(co_base + l15) * KT + g * 8;
#pragma unroll
    for (int cs = 0; cs < NCS; ++cs)
#pragma unroll
      for (int s = 0; s < NS; ++s)
        Af[cs][s] = *(const f16x8*)(wb + cs * 16 * KT + s * 32);
  }
  if (tid < COUT) {
    sst[0][tid] = scale[tid];
    sst[1][tid] = shift[tid];
  }

  auto stage_row = [&](int row) {  // row in [-1, ...]; clamped if > 256
    int rs = row > 256 ? 256 : row;
    const f16* src = x + ((size_t)(b * 258 + rs + 1) * 258 + w0) * CIN;
    f16* dst = xs[(row + 1) & 7];
    for (int c = tid; c < PERROW; c += 128) {
      int px = c / CC, cc = c - px * CC;
      int sz = (CIN == 64) ? (px & 7) : ((px >> 1) & 3);
      GLDS16(src + px * CIN + ((cc ^ sz) << 3), dst + c * 8);
    }
  };

#define PHASE_SYNC()                                                      \
  do {                                                                    \
    if (wco == 0)                                                         \
      asm volatile("s_waitcnt vmcnt(%0)" ::"i"(VN0) : "memory");          \
    else                                                                  \
      asm volatile("s_waitcnt vmcnt(%0)" ::"i"(VN1) : "memory");          \
    __builtin_amdgcn_s_barrier();                                         \
    __builtin_amdgcn_sched_barrier(0);                                    \
  } while (0)

  // prologue: rows h0-1 .. h0+4
  stage_row(h0 - 1); stage_row(h0);
  stage_row(h0 + 1); stage_row(h0 + 2);
  stage_row(h0 + 3); stage_row(h0 + 4);
  PHASE_SYNC();

#pragma unroll 1
  for (int hp = h0; hp < h0 + 32; hp += 2) {
#pragma unroll
    for (int r2 = 0; r2 < 2; ++r2) {
      stage_row(hp + 5 + r2);  // for phase p+2; completion enforced next barrier
      int h = hp + r2;

      f32x4 acc[NCS][PXW];
#pragma unroll
      for (int cs = 0; cs < NCS; ++cs)
#pragma unroll
        for (int p = 0; p < PXW; ++p) acc[cs][p] = (f32x4){0.f, 0.f, 0.f, 0.f};

      // one-hot class bytes (from padded map) — issue early
      int ia[PXW], ib[PXW], ic[PXW];
      if (ONEHOT) {
        int ta = 2 * g, tb = ta + 1;
        int dya = ta / 3, dxa = ta - 3 * dya;
        int dyb = tb / 3, dxb = tb - 3 * dyb;
#pragma unroll
        for (int pxb = 0; pxb < PXW; ++pxb) {
          int pxa = pxg + pxb * 16 + l15;
          ia[pxb] = fmap[(size_t)(b * 258 + h + dya) * 258 + w0 + pxa + dxa];
          ib[pxb] = fmap[(size_t)(b * 258 + h + dyb) * 258 + w0 + pxa + dxb];
          ic[pxb] = fmap[(size_t)(b * 258 + h + 2) * 258 + w0 + pxa + 2];
        }
      }

      const f16* sp0 = xs[h & 7];
      const f16* sp1 = xs[(h + 1) & 7];
      const f16* sp2 = xs[(h + 2) & 7];
#pragma unroll
      for (int tap = 0; tap < 9; ++tap) {
        const int dy = tap / 3, dx = tap - 3 * (tap / 3);
        const f16* sp = (dy == 0) ? sp0 : ((dy == 1) ? sp1 : sp2);
#pragma unroll
        for (int pxb = 0; pxb < PXW; ++pxb) {
          int pxd = pxg + pxb * 16 + l15 + dx;
          int sz = (CIN == 64) ? (pxd & 7) : ((pxd >> 1) & 3);
#pragma unroll
          for (int half = 0; half < NH; ++half) {
            f16x8 bb = *(const f16x8*)(sp + pxd * CIN + (((g + 4 * half) ^ sz) << 3));
#pragma unroll
            for (int cs = 0; cs < NCS; ++cs)
              acc[cs][pxb] = __builtin_amdgcn_mfma_f32_16x16x32_f16(
                  Af[cs][tap * NH + half], bb, acc[cs][pxb], 0, 0, 0);
          }
        }
      }
      if (ONEHOT) {
#pragma unroll
        for (int pxb = 0; pxb < PXW; ++pxb) {
          f16x8 b18, b19;
#pragma unroll
          for (int j = 0; j < 4; ++j) {
            b18[j] = (f16)((ia[pxb] == j) ? 1.f : 0.f);
            b18[j + 4] = (f16)((ib[pxb] == j) ? 1.f : 0.f);
            b19[j] = (f16)((g == 0 && ic[pxb] == j) ? 1.f : 0.f);
            b19[j + 4] = (f16)0.f;
          }
#pragma unroll
          for (int cs = 0; cs < NCS; ++cs) {
            acc[cs][pxb] = __builtin_amdgcn_mfma_f32_16x16x32_f16(
                Af[cs][NS - 2], b18, acc[cs][pxb], 0, 0, 0);
            acc[cs][pxb] = __builtin_amdgcn_mfma_f32_16x16x32_f16(
                Af[cs][NS - 1], b19, acc[cs][pxb], 0, 0, 0);
          }
        }
      }
      // epilogue: BN scale/shift + relu, fp16 store
#pragma unroll
      for (int cs = 0; cs < NCS; ++cs) {
        int cb = co_base + cs * 16 + 4 * g;
        f32x4 sv = *(const f32x4*)&sst[0][cb];
        f32x4 tv = *(const f32x4*)&sst[1][cb];
#pragma unroll
        for (int pxb = 0; pxb < PXW; ++pxb) {
          int px = pxg + pxb * 16 + l15;
          f16x4 o;
#pragma unroll
          for (int r = 0; r < 4; ++r)
            o[r] = (f16)fmaxf(acc[cs][pxb][r] * sv[r] + tv[r], 0.f);
          size_t oi =
              OUTPAD ? ((size_t)(b * 258 + h + 1) * 258 + (w0 + px + 1)) * 64 + cb
                     : ((size_t)(b * 256 + h) * 256 + (w0 + px)) * COUT + cb;
          *(f16x4*)&y[oi] = o;
        }
      }
    }
    PHASE_SYNC();
  }
#undef PHASE_SYNC
}

// ---- fused 1x1 conv (32->4) + softmax + wind conv + fire update ----
__global__ __launch_bounds__(256) void k_step(
    const f16* __restrict__ h2, const float* __restrict__ cw3,
    const float* __restrict__ cb3, const float* __restrict__ wke,
    const float* __restrict__ fin, float* __restrict__ fout,
    float* __restrict__ fout2) {
  __shared__ float wl[4][32];
  __shared__ float bl[4];
  __shared__ float wk[9];
  int tid = threadIdx.x;
  if (tid < 128) wl[tid >> 5][tid & 31] = cw3[tid];
  if (tid < 4) bl[tid] = cb3[tid];
  int bx = blockIdx.x;
  int b = bx >> 8, h = bx & 255;
  if (tid < 9) wk[tid] = wke[b * 9 + tid];
  __syncthreads();
  int w = tid;
  const f16x8* hp8 = (const f16x8*)(h2 + ((size_t)(b * 256 + h) * 256 + w) * 32);
  float l0 = bl[0], l1 = bl[1], l2 = bl[2], l3 = bl[3];
#pragma unroll
  for (int q = 0; q < 4; ++q) {
    f16x8 v8 = hp8[q];
#pragma unroll
    for (int j = 0; j < 8; ++j) {
      float v = (float)v8[j];
      int c = q * 8 + j;
      l0 += v * wl[0][c];
      l1 += v * wl[1][c];
      l2 += v * wl[2][c];
      l3 += v * wl[3][c];
    }
  }
  float mx = fmaxf(fmaxf(l0, l1), fmaxf(l2, l3));
  float e0 = expf(l0 - mx), e1 = expf(l1 - mx), e2 = expf(l2 - mx), e3 = expf(l3 - mx);
  float inv = 1.f / (e0 + e1 + e2 + e3);
  float p1 = e1 * inv, p2 = e2 * inv;
  const float* fp = fin + ((size_t)b << 16);
  float wacc = 0.f;
#pragma unroll
  for (int tap = 0; tap < 9; ++tap) {
    int dy = tap / 3 - 1, dx = tap % 3 - 1;
    int hh = h + dy, ww2 = w + dx;
    float f = ((unsigned)hh < 256u && (unsigned)ww2 < 256u) ? fp[(hh << 8) + ww2] : 0.f;
    wacc += wk[tap] * f;
  }
  float boost = 0.3f / (1.f + expf(-wacc));
  float fcur = fp[(h << 8) + w];
  float target = 0.5f * p1 + 0.5f * boost + p2;
  float fn = 0.7f * fcur + 0.3f * target;
  fn = fminf(fmaxf(fn, 0.f), 1.f);
  size_t o = ((size_t)b << 16) + (h << 8) + w;
  fout[o] = fn;
  if (fout2) fout2[o] = fn;
}

extern "C" void kernel_launch(void* const* d_in, const int* in_sizes, int n_in,
                              void* d_out, int out_size, void* d_ws, size_t ws_size,
                              hipStream_t stream) {
  const float* env = (const float*)d_in[0];
  const float* fire0 = (const float*)d_in[1];
  const float* w1 = (const float*)d_in[2];
  const float* b1 = (const float*)d_in[3];
  const float* g1 = (const float*)d_in[4];
  const float* be1 = (const float*)d_in[5];
  const float* m1 = (const float*)d_in[6];
  const float* v1 = (const float*)d_in[7];
  const float* w2 = (const float*)d_in[8];
  const float* b2 = (const float*)d_in[9];
  const float* g2 = (const float*)d_in[10];
  const float* be2 = (const float*)d_in[11];
  const float* m2 = (const float*)d_in[12];
  const float* v2 = (const float*)d_in[13];
  const float* cw1 = (const float*)d_in[14];
  const float* cb1 = (const float*)d_in[15];
  const float* cg1 = (const float*)d_in[16];
  const float* cbe1 = (const float*)d_in[17];
  const float* cm1 = (const float*)d_in[18];
  const float* cv1 = (const float*)d_in[19];
  const float* cw2 = (const float*)d_in[20];
  const float* cb2 = (const float*)d_in[21];
  const float* cg2 = (const float*)d_in[22];
  const float* cbe2 = (const float*)d_in[23];
  const float* cm2 = (const float*)d_in[24];
  const float* cv2 = (const float*)d_in[25];
  const float* cw3 = (const float*)d_in[26];
  const float* cb3 = (const float*)d_in[27];
  const float* windk = (const float*)d_in[28];
  // d_in[29] = num_steps (fixed 5)

  float* out = (float*)d_out;
  float* evo = out + 1048576;  // [6][16][1][256][256] fp32

  // ---- workspace layout ----
  uint8_t* p = (uint8_t*)d_ws;
  f16* W1p = (f16*)p;           p += 64 * 288 * 2;
  f16* W2p = (f16*)p;           p += 64 * 576 * 2;
  f16* Wc1p = (f16*)p;          p += 64 * 640 * 2;
  f16* Wc2p = (f16*)p;          p += 32 * 576 * 2;
  float* s1 = (float*)p;        p += 64 * 4;
  float* t1 = (float*)p;        p += 64 * 4;
  float* s2 = (float*)p;        p += 64 * 4;
  float* t2 = (float*)p;        p += 64 * 4;
  float* sc1 = (float*)p;       p += 64 * 4;
  float* tc1 = (float*)p;       p += 64 * 4;
  float* sc2 = (float*)p;       p += 64 * 4;
  float* tc2 = (float*)p;       p += 64 * 4;
  float* wke = (float*)p;       p += 1024;
  const size_t IMGP = (size_t)258 * 258 * 64;
  const size_t IMGP32 = (size_t)258 * 258 * 32;
  f16* envf = (f16*)p;          p += 16 * IMGP * 2;  // 136.3 MB
  size_t fixed = (size_t)(p - (uint8_t*)d_ws);
  int NB = 1;
  for (int nb = 16; nb >= 1; nb >>= 1) {
    size_t need = fixed + (size_t)nb * (IMGP * 2 + IMGP32 * 2 + 66564 + 256);
    if (need <= ws_size) { NB = nb; break; }
  }
  f16* h1p = (f16*)p;           p += (size_t)NB * IMGP * 2;
  f16* envin = (f16*)p;         // NB*IMGP32 elems, overlaid with h2 (time-disjoint)
  f16* h2 = envin;              p += (size_t)NB * IMGP32 * 2;
  unsigned char* fmap = (unsigned char*)p;  // NB*66564 bytes

  // ---- setup ----
  k_wprepC0<<<(64 * 288 + 255) / 256, 256, 0, stream>>>(w1, W1p);
  k_wprep64<<<(64 * 576 + 255) / 256, 256, 0, stream>>>(w2, W2p, 64);
  k_wprepC1<<<(64 * 640 + 255) / 256, 256, 0, stream>>>(cw1, Wc1p);
  k_wprep64<<<(32 * 576 + 255) / 256, 256, 0, stream>>>(cw2, Wc2p, 32);
  k_bnfuse<<<1, 256, 0, stream>>>(g1, be1, m1, v1, b1, s1, t1, 64);
  k_bnfuse<<<1, 256, 0, stream>>>(g2, be2, m2, v2, b2, s2, t2, 64);
  k_bnfuse<<<1, 256, 0, stream>>>(cg1, cbe1, cm1, cv1, cb1, sc1, tc1, 64);
  k_bnfuse<<<1, 256, 0, stream>>>(cg2, cbe2, cm2, cv2, cb2, sc2, tc2, 32);
  k_windgate<<<16, 256, 0, stream>>>(env, windk, wke);
  k_copy<<<1024, 256, 0, stream>>>(fire0, evo);
  k_border<<<(16 * 1028 * 64 + 255) / 256, 256, 0, stream>>>(envf, 16, 64);
  k_border<<<(NB * 1028 * 64 + 255) / 256, 256, 0, stream>>>(h1p, NB, 64);
  k_border<<<(NB * 1028 * 32 + 255) / 256, 256, 0, stream>>>(envin, NB, 32);

  const int gconv = NB * 64;  // width-32 strips x 8 hstrips (R=32)

  // encoder (chunked)
  for (int b0 = 0; b0 < 16; b0 += NB) {
    k_env2h<<<NB * 256, 256, 0, stream>>>(env + (size_t)b0 * 22 * HWSZ, envin, NB);
    k_convM<32, 2, 9, false, true, false, 3><<<gconv, 128, 0, stream>>>(
        envin, W1p, s1, t1, nullptr, h1p, NB);
    k_convM<64, 2, 18, false, true, false, 2><<<gconv, 128, 0, stream>>>(
        h1p, W2p, s2, t2, nullptr, envf + (size_t)b0 * IMGP, NB);
  }
  // CA steps (chunked)
  for (int t = 0; t < 5; ++t) {
    const float* fin = evo + (size_t)t * 1048576;
    float* fo = evo + (size_t)(t + 1) * 1048576;
    for (int b0 = 0; b0 < 16; b0 += NB) {
      k_firemap<<<(NB * 66564 + 255) / 256, 256, 0, stream>>>(
          fin + (size_t)b0 * HWSZ, fmap, NB);
      k_convM<64, 2, 20, true, true, false, 2><<<gconv, 128, 0, stream>>>(
          envf + (size_t)b0 * IMGP, Wc1p, sc1, tc1, fmap, h1p, NB);
      k_convM<64, 2, 18, false, false, true, 2><<<gconv, 128, 0, stream>>>(
          h1p, Wc2p, sc2, tc2, nullptr, h2, NB);
      k_step<<<NB * 256, 256, 0, stream>>>(
          h2, cw3, cb3, wke + (size_t)b0 * 9, fin + (size_t)b0 * HWSZ,
          fo + (size_t)b0 * HWSZ, (t == 4) ? out + (size_t)b0 * HWSZ : nullptr);
    }
  }
}

// Round 6
// 1115.185 us; speedup vs baseline: 10.5660x; 1.1055x over previous
//
#include <hip/hip_runtime.h>
#include <cstdint>
#include <cstddef>

// LearnableCA fire-spread, round 6: fix latency-bound windgate (was 122us at
// 0.65% occupancy) via two-stage deterministic reduction; fuse fire-class-map
// generation into k_step (map for step t+1 written by step t).
// Convs unchanged from round 5 (counted-vmcnt pipelined MFMA).

#define HWSZ 65536

typedef _Float16 f16;
typedef f16 f16x8 __attribute__((ext_vector_type(8)));
typedef f16 f16x4 __attribute__((ext_vector_type(4)));
typedef float f32x4 __attribute__((ext_vector_type(4)));

#define GLDS16(gp, lp)                                                        \
  __builtin_amdgcn_global_load_lds(                                           \
      (const __attribute__((address_space(1))) void*)(gp),                    \
      (__attribute__((address_space(3))) void*)(lp), 16, 0, 0)

// ---- conv1 weight prep: [64][22][3][3] -> [co][tap*32+ci], ci7 x64, pad->32 ----
__global__ void k_wprepC0(const float* __restrict__ src, f16* __restrict__ dst) {
  int i = blockIdx.x * 256 + threadIdx.x;
  if (i >= 64 * 288) return;
  int co = i / 288, k = i - co * 288;
  int tap = k >> 5, ci = k & 31;
  float v = 0.f;
  if (ci < 22) {
    v = src[(co * 22 + ci) * 9 + tap];
    if (ci == 7) v *= 64.f;
  }
  dst[i] = (f16)v;
}

// ---- fp16 weight prep: [co][ci 64][3][3] -> [co][tap*64+ci] ----
__global__ void k_wprep64(const float* __restrict__ src, f16* __restrict__ dst,
                          int COUT) {
  int i = blockIdx.x * 256 + threadIdx.x;
  if (i >= COUT * 576) return;
  int co = i / 576, k = i - co * 576;
  int tap = k >> 6, ci = k & 63;
  dst[i] = (f16)src[(co * 64 + ci) * 9 + tap];
}

// ---- cw1 prep: 64 normal ci + one-hot block (kl = tap*4+oc) -> [co][640] ----
__global__ void k_wprepC1(const float* __restrict__ src, f16* __restrict__ dst) {
  int i = blockIdx.x * 256 + threadIdx.x;
  if (i >= 64 * 640) return;
  int co = i / 640, k = i - co * 640;
  float v;
  if (k < 576) {
    int tap = k >> 6, ci = k & 63;
    v = src[(co * 68 + ci) * 9 + tap];
  } else {
    int kl = k - 576;
    int oc = kl & 3, tp = kl >> 2;
    v = (tp < 9) ? src[(co * 68 + 64 + oc) * 9 + tp] : 0.f;
  }
  dst[i] = (f16)v;
}

// ---- fold BN + conv bias into per-channel scale/shift ----
__global__ void k_bnfuse(const float* __restrict__ g, const float* __restrict__ be,
                         const float* __restrict__ m, const float* __restrict__ v,
                         const float* __restrict__ bc, float* __restrict__ s,
                         float* __restrict__ t, int C) {
  int c = threadIdx.x;
  if (c < C) {
    float sc = g[c] * rsqrtf(v[c] + 1e-5f);
    s[c] = sc;
    t[c] = (bc[c] - m[c]) * sc + be[c];
  }
}

// ---- wind reduction stage 1: 32 partials per batch, double, deterministic ----
__global__ __launch_bounds__(256) void k_windpart(const float* __restrict__ env,
                                                  double* __restrict__ part) {
  int blk = blockIdx.x;
  int b = blk >> 5, j = blk & 31;
  const float4* a7 = (const float4*)(env + (((size_t)(b * 22 + 7)) << 16) + j * 2048);
  const float4* a8 = (const float4*)(env + (((size_t)(b * 22 + 8)) << 16) + j * 2048);
  int tid = threadIdx.x;
  double s7 = 0.0, s8 = 0.0;
  for (int i = tid; i < 512; i += 256) {
    float4 v = a7[i];
    s7 += (double)v.x + (double)v.y + (double)v.z + (double)v.w;
    float4 u = a8[i];
    s8 += (double)u.x + (double)u.y + (double)u.z + (double)u.w;
  }
  __shared__ double r7[256], r8[256];
  r7[tid] = s7; r8[tid] = s8;
  __syncthreads();
  for (int off = 128; off > 0; off >>= 1) {
    if (tid < off) { r7[tid] += r7[tid + off]; r8[tid] += r8[tid + off]; }
    __syncthreads();
  }
  if (tid == 0) {
    part[(b * 32 + j) * 2 + 0] = r7[0];
    part[(b * 32 + j) * 2 + 1] = r8[0];
  }
}

// ---- wind reduction stage 2: combine partials, compute effective 3x3 kernel ----
__global__ void k_windfin(const double* __restrict__ part,
                          const float* __restrict__ wind_k, float* __restrict__ wke) {
  int b = blockIdx.x;
  if (threadIdx.x != 0) return;
  double s7 = 0.0, s8 = 0.0;
  for (int j = 0; j < 32; ++j) {
    s7 += part[(b * 32 + j) * 2 + 0];
    s8 += part[(b * 32 + j) * 2 + 1];
  }
  float wa = (float)(s7 * (1.0 / 65536.0));
  float wsp = (float)(s8 * (1.0 / 65536.0));
  float wsc = fminf(fmaxf(wsp * (1.f / 20.f), 0.f), 1.f);
  float wk[9];
#pragma unroll
  for (int tp = 0; tp < 9; ++tp) wk[tp] = 0.f;
  for (int d = 0; d < 8; ++d) {
    float diff = fabsf(wa - 45.f * (float)d);
    diff = fminf(diff, 360.f - diff);
    float dw = fmaxf(0.f, 1.f - diff * (1.f / 90.f));
    float eff = (dw > 0.1f && wsc > 0.1f) ? dw * wsc : 0.f;
    for (int tp = 0; tp < 9; ++tp) wk[tp] += eff * wind_k[d * 9 + tp];
  }
  for (int tp = 0; tp < 9; ++tp) wke[b * 9 + tp] = wk[tp];
}

__global__ void k_copy(const float* __restrict__ src, float* __restrict__ dst) {
  int i = blockIdx.x * 256 + threadIdx.x;
  ((float4*)dst)[i] = ((const float4*)src)[i];
}

// ---- zero the 1-px border of a padded NHWC buffer [n][258][258][C] ----
__global__ void k_border(f16* __restrict__ buf, int nimg, int C) {
  int i = blockIdx.x * 256 + threadIdx.x;
  int per = 1028 * C;
  if (i >= nimg * per) return;
  int img = i / per, r = i - img * per;
  int px = r / C, c = r - px * C;
  int h, w;
  if (px < 258) { h = 0; w = px; }
  else if (px < 516) { h = 257; w = px - 258; }
  else if (px < 772) { h = px - 515; w = 0; }
  else { h = px - 771; w = 257; }
  buf[((size_t)(img * 258 + h) * 258 + w) * C + c] = (f16)0.f;
}

// ---- env NCHW fp32 -> padded NHWC fp16 [258][258][32], ch7 * 1/64 ----
__global__ __launch_bounds__(256) void k_env2h(const float* __restrict__ env,
                                               f16* __restrict__ dst, int nimg) {
  int i = blockIdx.x * 256 + threadIdx.x;
  if (i >= (nimg << 16)) return;
  int b = i >> 16, hw = i & 65535;
  int h = hw >> 8, w = hw & 255;
  const float* sp = env + (((size_t)b * 22) << 16) + hw;
  f16 o[32];
#pragma unroll
  for (int c = 0; c < 22; ++c) {
    float v = sp[(size_t)c << 16];
    if (c == 7) v *= (1.f / 64.f);
    o[c] = (f16)v;
  }
#pragma unroll
  for (int c = 22; c < 32; ++c) o[c] = (f16)0.f;
  f16* dp = dst + ((size_t)(b * 258 + h + 1) * 258 + (w + 1)) * 32;
  *(f16x8*)(dp + 0) = *(f16x8*)&o[0];
  *(f16x8*)(dp + 8) = *(f16x8*)&o[8];
  *(f16x8*)(dp + 16) = *(f16x8*)&o[16];
  *(f16x8*)(dp + 24) = *(f16x8*)&o[24];
}

// ---- padded uint8 fire-class map: [b][258][258], border=4 (initial seed) ----
__global__ void k_firemap(const float* __restrict__ fire, unsigned char* __restrict__ map,
                          int nimg) {
  int i = blockIdx.x * 256 + threadIdx.x;
  if (i >= nimg * 66564) return;
  int b = i / 66564, r = i - b * 66564;
  int h = r / 258, w = r - h * 258;
  unsigned char v = 4;
  if (h >= 1 && h <= 256 && w >= 1 && w <= 256) {
    float f = fire[((size_t)b << 16) + ((h - 1) << 8) + (w - 1)];
    v = f < 0.25f ? 0 : (f < 0.75f ? 1 : 2);
  }
  map[i] = v;
}

// ---- MFMA conv, pipelined: CIN in {32,64}, width-32 tile, R=32 rows/block ----
// 128 threads = 2 waves. PXSPLIT=false: waves split couts (COUT=NCS*32);
// PXSPLIT=true: waves split pixels, each does all COUT=NCS*16 couts.
template <int CIN, int NCS, int NS, bool ONEHOT, bool OUTPAD, bool PXSPLIT, int MINW>
__global__ __launch_bounds__(128, MINW) void k_convM(
    const f16* __restrict__ x, const f16* __restrict__ Wp,
    const float* __restrict__ scale, const float* __restrict__ shift,
    const unsigned char* __restrict__ fmap, f16* __restrict__ y, int NB) {
  constexpr int COUT = PXSPLIT ? NCS * 16 : NCS * 32;
  constexpr int KT = NS * 32;
  constexpr int CC = CIN / 8;           // 16B chunks per px
  constexpr int PERROW = 34 * CC;       // 16B chunks per staged row
  constexpr int ROWE = 34 * CIN;        // f16 per row slot
  constexpr int PXW = PXSPLIT ? 1 : 2;  // px-frag groups per wave
  constexpr int NH = CIN / 32;          // k-halves per tap
  // stage instr counts per wave per 2-row phase (wave0 gets the ragged tail)
  constexpr int VN0 = (CIN == 64) ? 6 : 4;
  constexpr int VN1 = (CIN == 64) ? 4 : 2;

  __shared__ __align__(16) f16 xs[8][ROWE];
  __shared__ float sst[2][COUT];

  int tid = threadIdx.x;
  int lane = tid & 63;
  int l15 = lane & 15;
  int g = (lane >> 4) & 3;
  int wco = tid >> 6;

  // block decode with XCD band grouping: d%8 = hs constant per band
  int d = blockIdx.x;
  int hsn = NB * 8;
  int ws = d / hsn;
  int t = d - ws * hsn;
  int b = t >> 3;
  int hs = t & 7;
  int w0 = ws * 32, h0 = hs * 32;

  int co_base = PXSPLIT ? 0 : wco * NCS * 16;
  int pxg = PXSPLIT ? wco * 16 : 0;

  // weights -> registers/AGPRs
  f16x8 Af[NCS][NS];
  {
    const f16* wb = Wp + (size_t)(co_base + l15) * KT + g * 8;
#pragma unroll
    for (int cs = 0; cs < NCS; ++cs)
#pragma unroll
      for (int s = 0; s < NS; ++s)
        Af[cs][s] = *(const f16x8*)(wb + cs * 16 * KT + s * 32);
  }
  if (tid < COUT) {
    sst[0][tid] = scale[tid];
    sst[1][tid] = shift[tid];
  }

  auto stage_row = [&](int row) {  // row in [-1, ...]; clamped if > 256
    int rs = row > 256 ? 256 : row;
    const f16* src = x + ((size_t)(b * 258 + rs + 1) * 258 + w0) * CIN;
    f16* dst = xs[(row + 1) & 7];
    for (int c = tid; c < PERROW; c += 128) {
      int px = c / CC, cc = c - px * CC;
      int sz = (CIN == 64) ? (px & 7) : ((px >> 1) & 3);
      GLDS16(src + px * CIN + ((cc ^ sz) << 3), dst + c * 8);
    }
  };

#define PHASE_SYNC()                                                      \
  do {                                                                    \
    if (wco == 0)                                                         \
      asm volatile("s_waitcnt vmcnt(%0)" ::"i"(VN0) : "memory");          \
    else                                                                  \
      asm volatile("s_waitcnt vmcnt(%0)" ::"i"(VN1) : "memory");          \
    __builtin_amdgcn_s_barrier();                                         \
    __builtin_amdgcn_sched_barrier(0);                                    \
  } while (0)

  // prologue: rows h0-1 .. h0+4
  stage_row(h0 - 1); stage_row(h0);
  stage_row(h0 + 1); stage_row(h0 + 2);
  stage_row(h0 + 3); stage_row(h0 + 4);
  PHASE_SYNC();

#pragma unroll 1
  for (int hp = h0; hp < h0 + 32; hp += 2) {
#pragma unroll
    for (int r2 = 0; r2 < 2; ++r2) {
      stage_row(hp + 5 + r2);  // for phase p+2; completion enforced next barrier
      int h = hp + r2;

      f32x4 acc[NCS][PXW];
#pragma unroll
      for (int cs = 0; cs < NCS; ++cs)
#pragma unroll
        for (int p = 0; p < PXW; ++p) acc[cs][p] = (f32x4){0.f, 0.f, 0.f, 0.f};

      // one-hot class bytes (from padded map) — issue early
      int ia[PXW], ib[PXW], ic[PXW];
      if (ONEHOT) {
        int ta = 2 * g, tb = ta + 1;
        int dya = ta / 3, dxa = ta - 3 * dya;
        int dyb = tb / 3, dxb = tb - 3 * dyb;
#pragma unroll
        for (int pxb = 0; pxb < PXW; ++pxb) {
          int pxa = pxg + pxb * 16 + l15;
          ia[pxb] = fmap[(size_t)(b * 258 + h + dya) * 258 + w0 + pxa + dxa];
          ib[pxb] = fmap[(size_t)(b * 258 + h + dyb) * 258 + w0 + pxa + dxb];
          ic[pxb] = fmap[(size_t)(b * 258 + h + 2) * 258 + w0 + pxa + 2];
        }
      }

      const f16* sp0 = xs[h & 7];
      const f16* sp1 = xs[(h + 1) & 7];
      const f16* sp2 = xs[(h + 2) & 7];
#pragma unroll
      for (int tap = 0; tap < 9; ++tap) {
        const int dy = tap / 3, dx = tap - 3 * (tap / 3);
        const f16* sp = (dy == 0) ? sp0 : ((dy == 1) ? sp1 : sp2);
#pragma unroll
        for (int pxb = 0; pxb < PXW; ++pxb) {
          int pxd = pxg + pxb * 16 + l15 + dx;
          int sz = (CIN == 64) ? (pxd & 7) : ((pxd >> 1) & 3);
#pragma unroll
          for (int half = 0; half < NH; ++half) {
            f16x8 bb = *(const f16x8*)(sp + pxd * CIN + (((g + 4 * half) ^ sz) << 3));
#pragma unroll
            for (int cs = 0; cs < NCS; ++cs)
              acc[cs][pxb] = __builtin_amdgcn_mfma_f32_16x16x32_f16(
                  Af[cs][tap * NH + half], bb, acc[cs][pxb], 0, 0, 0);
          }
        }
      }
      if (ONEHOT) {
#pragma unroll
        for (int pxb = 0; pxb < PXW; ++pxb) {
          f16x8 b18, b19;
#pragma unroll
          for (int j = 0; j < 4; ++j) {
            b18[j] = (f16)((ia[pxb] == j) ? 1.f : 0.f);
            b18[j + 4] = (f16)((ib[pxb] == j) ? 1.f : 0.f);
            b19[j] = (f16)((g == 0 && ic[pxb] == j) ? 1.f : 0.f);
            b19[j + 4] = (f16)0.f;
          }
#pragma unroll
          for (int cs = 0; cs < NCS; ++cs) {
            acc[cs][pxb] = __builtin_amdgcn_mfma_f32_16x16x32_f16(
                Af[cs][NS - 2], b18, acc[cs][pxb], 0, 0, 0);
            acc[cs][pxb] = __builtin_amdgcn_mfma_f32_16x16x32_f16(
                Af[cs][NS - 1], b19, acc[cs][pxb], 0, 0, 0);
          }
        }
      }
      // epilogue: BN scale/shift + relu, fp16 store
#pragma unroll
      for (int cs = 0; cs < NCS; ++cs) {
        int cb = co_base + cs * 16 + 4 * g;
        f32x4 sv = *(const f32x4*)&sst[0][cb];
        f32x4 tv = *(const f32x4*)&sst[1][cb];
#pragma unroll
        for (int pxb = 0; pxb < PXW; ++pxb) {
          int px = pxg + pxb * 16 + l15;
          f16x4 o;
#pragma unroll
          for (int r = 0; r < 4; ++r)
            o[r] = (f16)fmaxf(acc[cs][pxb][r] * sv[r] + tv[r], 0.f);
          size_t oi =
              OUTPAD ? ((size_t)(b * 258 + h + 1) * 258 + (w0 + px + 1)) * 64 + cb
                     : ((size_t)(b * 256 + h) * 256 + (w0 + px)) * COUT + cb;
          *(f16x4*)&y[oi] = o;
        }
      }
    }
    PHASE_SYNC();
  }
#undef PHASE_SYNC
}

// ---- fused 1x1 conv (32->4) + softmax + wind conv + fire update + next map ----
__global__ __launch_bounds__(256) void k_step(
    const f16* __restrict__ h2, const float* __restrict__ cw3,
    const float* __restrict__ cb3, const float* __restrict__ wke,
    const float* __restrict__ fin, float* __restrict__ fout,
    float* __restrict__ fout2, unsigned char* __restrict__ mapout) {
  __shared__ float wl[4][32];
  __shared__ float bl[4];
  __shared__ float wk[9];
  int tid = threadIdx.x;
  if (tid < 128) wl[tid >> 5][tid & 31] = cw3[tid];
  if (tid < 4) bl[tid] = cb3[tid];
  int bx = blockIdx.x;
  int b = bx >> 8, h = bx & 255;
  if (tid < 9) wk[tid] = wke[b * 9 + tid];
  __syncthreads();
  int w = tid;
  const f16x8* hp8 = (const f16x8*)(h2 + ((size_t)(b * 256 + h) * 256 + w) * 32);
  float l0 = bl[0], l1 = bl[1], l2 = bl[2], l3 = bl[3];
#pragma unroll
  for (int q = 0; q < 4; ++q) {
    f16x8 v8 = hp8[q];
#pragma unroll
    for (int j = 0; j < 8; ++j) {
      float v = (float)v8[j];
      int c = q * 8 + j;
      l0 += v * wl[0][c];
      l1 += v * wl[1][c];
      l2 += v * wl[2][c];
      l3 += v * wl[3][c];
    }
  }
  float mx = fmaxf(fmaxf(l0, l1), fmaxf(l2, l3));
  float e0 = expf(l0 - mx), e1 = expf(l1 - mx), e2 = expf(l2 - mx), e3 = expf(l3 - mx);
  float inv = 1.f / (e0 + e1 + e2 + e3);
  float p1 = e1 * inv, p2 = e2 * inv;
  const float* fp = fin + ((size_t)b << 16);
  float wacc = 0.f;
#pragma unroll
  for (int tap = 0; tap < 9; ++tap) {
    int dy = tap / 3 - 1, dx = tap % 3 - 1;
    int hh = h + dy, ww2 = w + dx;
    float f = ((unsigned)hh < 256u && (unsigned)ww2 < 256u) ? fp[(hh << 8) + ww2] : 0.f;
    wacc += wk[tap] * f;
  }
  float boost = 0.3f / (1.f + expf(-wacc));
  float fcur = fp[(h << 8) + w];
  float target = 0.5f * p1 + 0.5f * boost + p2;
  float fn = 0.7f * fcur + 0.3f * target;
  fn = fminf(fmaxf(fn, 0.f), 1.f);
  size_t o = ((size_t)b << 16) + (h << 8) + w;
  fout[o] = fn;
  if (fout2) fout2[o] = fn;
  // fire-class map for the next step's cw1 (border stays 4, written once at init)
  mapout[(size_t)(b * 258 + h + 1) * 258 + (w + 1)] =
      fn < 0.25f ? (unsigned char)0 : (fn < 0.75f ? (unsigned char)1 : (unsigned char)2);
}

extern "C" void kernel_launch(void* const* d_in, const int* in_sizes, int n_in,
                              void* d_out, int out_size, void* d_ws, size_t ws_size,
                              hipStream_t stream) {
  const float* env = (const float*)d_in[0];
  const float* fire0 = (const float*)d_in[1];
  const float* w1 = (const float*)d_in[2];
  const float* b1 = (const float*)d_in[3];
  const float* g1 = (const float*)d_in[4];
  const float* be1 = (const float*)d_in[5];
  const float* m1 = (const float*)d_in[6];
  const float* v1 = (const float*)d_in[7];
  const float* w2 = (const float*)d_in[8];
  const float* b2 = (const float*)d_in[9];
  const float* g2 = (const float*)d_in[10];
  const float* be2 = (const float*)d_in[11];
  const float* m2 = (const float*)d_in[12];
  const float* v2 = (const float*)d_in[13];
  const float* cw1 = (const float*)d_in[14];
  const float* cb1 = (const float*)d_in[15];
  const float* cg1 = (const float*)d_in[16];
  const float* cbe1 = (const float*)d_in[17];
  const float* cm1 = (const float*)d_in[18];
  const float* cv1 = (const float*)d_in[19];
  const float* cw2 = (const float*)d_in[20];
  const float* cb2 = (const float*)d_in[21];
  const float* cg2 = (const float*)d_in[22];
  const float* cbe2 = (const float*)d_in[23];
  const float* cm2 = (const float*)d_in[24];
  const float* cv2 = (const float*)d_in[25];
  const float* cw3 = (const float*)d_in[26];
  const float* cb3 = (const float*)d_in[27];
  const float* windk = (const float*)d_in[28];
  // d_in[29] = num_steps (fixed 5)

  float* out = (float*)d_out;
  float* evo = out + 1048576;  // [6][16][1][256][256] fp32

  // ---- workspace layout ----
  uint8_t* p = (uint8_t*)d_ws;
  f16* W1p = (f16*)p;           p += 64 * 288 * 2;
  f16* W2p = (f16*)p;           p += 64 * 576 * 2;
  f16* Wc1p = (f16*)p;          p += 64 * 640 * 2;
  f16* Wc2p = (f16*)p;          p += 32 * 576 * 2;
  float* s1 = (float*)p;        p += 64 * 4;
  float* t1 = (float*)p;        p += 64 * 4;
  float* s2 = (float*)p;        p += 64 * 4;
  float* t2 = (float*)p;        p += 64 * 4;
  float* sc1 = (float*)p;       p += 64 * 4;
  float* tc1 = (float*)p;       p += 64 * 4;
  float* sc2 = (float*)p;       p += 64 * 4;
  float* tc2 = (float*)p;       p += 64 * 4;
  float* wke = (float*)p;       p += 1024;
  double* wpart = (double*)p;   p += 16 * 32 * 2 * 8;    // 8 KB
  unsigned char* fmap = p;      p += 16 * 66564 + 1024;  // all 16 batches, ~1 MB
  const size_t IMGP = (size_t)258 * 258 * 64;
  const size_t IMGP32 = (size_t)258 * 258 * 32;
  f16* envf = (f16*)p;          p += 16 * IMGP * 2;      // 136.3 MB
  size_t fixed = (size_t)(p - (uint8_t*)d_ws);
  int NB = 1;
  for (int nb = 16; nb >= 1; nb >>= 1) {
    size_t need = fixed + (size_t)nb * (IMGP * 2 + IMGP32 * 2);
    if (need <= ws_size) { NB = nb; break; }
  }
  f16* h1p = (f16*)p;           p += (size_t)NB * IMGP * 2;
  f16* envin = (f16*)p;         // NB*IMGP32 elems, overlaid with h2 (time-disjoint)
  f16* h2 = envin;

  // ---- setup ----
  k_wprepC0<<<(64 * 288 + 255) / 256, 256, 0, stream>>>(w1, W1p);
  k_wprep64<<<(64 * 576 + 255) / 256, 256, 0, stream>>>(w2, W2p, 64);
  k_wprepC1<<<(64 * 640 + 255) / 256, 256, 0, stream>>>(cw1, Wc1p);
  k_wprep64<<<(32 * 576 + 255) / 256, 256, 0, stream>>>(cw2, Wc2p, 32);
  k_bnfuse<<<1, 256, 0, stream>>>(g1, be1, m1, v1, b1, s1, t1, 64);
  k_bnfuse<<<1, 256, 0, stream>>>(g2, be2, m2, v2, b2, s2, t2, 64);
  k_bnfuse<<<1, 256, 0, stream>>>(cg1, cbe1, cm1, cv1, cb1, sc1, tc1, 64);
  k_bnfuse<<<1, 256, 0, stream>>>(cg2, cbe2, cm2, cv2, cb2, sc2, tc2, 32);
  k_windpart<<<512, 256, 0, stream>>>(env, wpart);
  k_windfin<<<16, 64, 0, stream>>>(wpart, windk, wke);
  k_copy<<<1024, 256, 0, stream>>>(fire0, evo);
  k_firemap<<<(16 * 66564 + 255) / 256, 256, 0, stream>>>(fire0, fmap, 16);
  k_border<<<(16 * 1028 * 64 + 255) / 256, 256, 0, stream>>>(envf, 16, 64);
  k_border<<<(NB * 1028 * 64 + 255) / 256, 256, 0, stream>>>(h1p, NB, 64);
  k_border<<<(NB * 1028 * 32 + 255) / 256, 256, 0, stream>>>(envin, NB, 32);

  const int gconv = NB * 64;  // width-32 strips x 8 hstrips (R=32)

  // encoder (chunked)
  for (int b0 = 0; b0 < 16; b0 += NB) {
    k_env2h<<<NB * 256, 256, 0, stream>>>(env + (size_t)b0 * 22 * HWSZ, envin, NB);
    k_convM<32, 2, 9, false, true, false, 3><<<gconv, 128, 0, stream>>>(
        envin, W1p, s1, t1, nullptr, h1p, NB);
    k_convM<64, 2, 18, false, true, false, 2><<<gconv, 128, 0, stream>>>(
        h1p, W2p, s2, t2, nullptr, envf + (size_t)b0 * IMGP, NB);
  }
  // CA steps (chunked)
  for (int t = 0; t < 5; ++t) {
    const float* fin = evo + (size_t)t * 1048576;
    float* fo = evo + (size_t)(t + 1) * 1048576;
    for (int b0 = 0; b0 < 16; b0 += NB) {
      k_convM<64, 2, 20, true, true, false, 2><<<gconv, 128, 0, stream>>>(
          envf + (size_t)b0 * IMGP, Wc1p, sc1, tc1, fmap + (size_t)b0 * 66564, h1p, NB);
      k_convM<64, 2, 18, false, false, true, 2><<<gconv, 128, 0, stream>>>(
          h1p, Wc2p, sc2, tc2, nullptr, h2, NB);
      k_step<<<NB * 256, 256, 0, stream>>>(
          h2, cw3, cb3, wke + (size_t)b0 * 9, fin + (size_t)b0 * HWSZ,
          fo + (size_t)b0 * HWSZ, (t == 4) ? out + (size_t)b0 * HWSZ : nullptr,
          fmap + (size_t)b0 * 66564);
    }
  }
}